// Round 1
// baseline (11769.345 us; speedup 1.0000x reference)
//
#include <hip/hip_runtime.h>

#define NN 50000
#define EE 800000
#define BB 64
#define EMB_D 16

// ---------------- K0: gather embedding ----------------
__global__ void k_gather(const int* __restrict__ node_idx,
                         const float* __restrict__ emb,
                         float* __restrict__ x) {
  int i = blockIdx.x * blockDim.x + threadIdx.x;
  if (i >= NN * EMB_D) return;
  int n = i >> 4;
  int j = i & 15;
  x[i] = emb[node_idx[n] * EMB_D + j];
}

// ---------------- K1: fused q,k,v,skip GEMMs ----------------
// block = 256 threads: 64 nodes x 4 column-groups. x tile staged in LDS.
// W index is wave-uniform -> scalar loads.
template <int FIN, int HC>
__global__ __launch_bounds__(256) void k_qkvs(
    const float* __restrict__ x, const float* __restrict__ Wq,
    const float* __restrict__ Wk, const float* __restrict__ Wv,
    const float* __restrict__ Ws, const float* __restrict__ bq,
    const float* __restrict__ bk, const float* __restrict__ bv,
    const float* __restrict__ bs, float* __restrict__ q,
    float* __restrict__ k, float* __restrict__ v, float* __restrict__ skip) {
  constexpr int JPG = HC / 4;  // columns per thread
  __shared__ float xs[64 * FIN];
  const int nb = blockIdx.x * 64;
  const int tid = threadIdx.x;
  const int rows = min(64, NN - nb);
  for (int i = tid; i < rows * FIN; i += 256) xs[i] = x[(size_t)nb * FIN + i];
  __syncthreads();
  const int node = tid & 63;
  const int cg = tid >> 6;
  const int j0 = cg * JPG;
  const int n = nb + node;
  if (n >= NN) return;
  const float* W[4] = {Wq, Wk, Wv, Ws};
  const float* bias[4] = {bq, bk, bv, bs};
  float* out[4] = {q, k, v, skip};
#pragma unroll
  for (int m = 0; m < 4; ++m) {
    const float* __restrict__ Wm = W[m];
    float acc[JPG];
#pragma unroll
    for (int j = 0; j < JPG; ++j) acc[j] = bias[m][j0 + j];
    for (int kc = 0; kc < FIN; kc += 16) {
      float xv[16];
#pragma unroll
      for (int kk = 0; kk < 16; ++kk) xv[kk] = xs[node * FIN + kc + kk];
#pragma unroll
      for (int kk = 0; kk < 16; ++kk) {
#pragma unroll
        for (int j = 0; j < JPG; ++j)
          acc[j] += xv[kk] * Wm[(kc + kk) * HC + j0 + j];
      }
    }
    float* o = out[m] + (size_t)n * HC + j0;
#pragma unroll
    for (int j = 0; j < JPG; ++j) o[j] = acc[j];
  }
}

// ---------------- K2: edge attention + aggregation (atomics) ----------------
constexpr float scale_of(int c) {
  return c == 32 ? 0.17677669529663687f
                 : (c == 64 ? 0.125f : 0.10206207261596575f);
}

template <int H, int C>
__global__ __launch_bounds__(256) void k_edge(
    const int* __restrict__ ei, const float* __restrict__ q,
    const float* __restrict__ k, const float* __restrict__ v,
    float* __restrict__ agg, float* __restrict__ denom) {
  constexpr int HC = H * C;
  const int idx = blockIdx.x * 256 + threadIdx.x;
  if (idx >= EE * H) return;
  const int e = idx % EE;
  const int hh = idx / EE;
  const int src = ei[e];
  const int dst = ei[EE + e];
  const float4* qp = (const float4*)(q + (size_t)dst * HC + hh * C);
  const float4* kp = (const float4*)(k + (size_t)src * HC + hh * C);
  float dot = 0.f;
#pragma unroll
  for (int i = 0; i < C / 4; ++i) {
    float4 a = qp[i];
    float4 b = kp[i];
    dot += a.x * b.x + a.y * b.y + a.z * b.z + a.w * b.w;
  }
  // softmax shift-invariance: skip segment_max (scores are O(1), no overflow)
  const float ea = expf(dot * scale_of(C));
  atomicAdd(denom + (size_t)dst * H + hh, ea);
  const float4* vp = (const float4*)(v + (size_t)src * HC + hh * C);
  float* ap = agg + (size_t)dst * HC + hh * C;
#pragma unroll
  for (int i = 0; i < C / 4; ++i) {
    float4 vv = vp[i];
    atomicAdd(ap + 4 * i + 0, vv.x * ea);
    atomicAdd(ap + 4 * i + 1, vv.y * ea);
    atomicAdd(ap + 4 * i + 2, vv.z * ea);
    atomicAdd(ap + 4 * i + 3, vv.w * ea);
  }
}

// ---------------- K3: divide by denom, add skip ----------------
template <int H, int C>
__global__ void k_fix(float* __restrict__ xout, const float* __restrict__ agg,
                      const float* __restrict__ denom) {
  constexpr int HC = H * C;
  const int i = blockIdx.x * 256 + threadIdx.x;
  if (i >= NN * HC) return;
  const int n = i / HC;
  const int hh = (i % HC) / C;
  xout[i] += agg[i] / (denom[(size_t)n * H + hh] + 1e-16f);
}

// ---------------- K4: segment-mean pool ----------------
__device__ __forceinline__ int lowerb(const int* __restrict__ b, int n,
                                      int key) {
  int lo = 0, hi = n;
  while (lo < hi) {
    int mid = (lo + hi) >> 1;
    if (b[mid] < key) lo = mid + 1;
    else hi = mid;
  }
  return lo;
}

__global__ void k_pool(const float* __restrict__ x,
                       const int* __restrict__ batch, float* __restrict__ g) {
  const int b = blockIdx.x;
  const int lo = lowerb(batch, NN, b);
  const int hi = lowerb(batch, NN, b + 1);
  const int j = threadIdx.x & 63;
  const int r = threadIdx.x >> 6;
  float acc = 0.f;
  for (int n = lo + r; n < hi; n += 4) acc += x[(size_t)n * 64 + j];
  __shared__ float red[256];
  red[threadIdx.x] = acc;
  __syncthreads();
  if (threadIdx.x < 64) {
    float s = red[j] + red[64 + j] + red[128 + j] + red[192 + j];
    int cnt = hi - lo;
    g[b * 64 + j] = s / (float)max(cnt, 1);
  }
}

// ---------------- K5: final MLP ----------------
__global__ void k_mlp(const float* __restrict__ g,
                      const float* __restrict__ demo,
                      const float* __restrict__ W1,
                      const float* __restrict__ b1,
                      const float* __restrict__ W2,
                      const float* __restrict__ b2, float* __restrict__ out) {
  const int b = threadIdx.x;
  if (b >= BB) return;
  float f[69];
#pragma unroll
  for (int t = 0; t < 64; ++t) f[t] = g[b * 64 + t];
#pragma unroll
  for (int t = 0; t < 5; ++t) f[64 + t] = demo[b * 5 + t];
  float o0 = b2[0], o1 = b2[1];
  for (int jm = 0; jm < 32; ++jm) {
    float h = b1[jm];
#pragma unroll
    for (int t = 0; t < 69; ++t) h += f[t] * W1[t * 32 + jm];
    h = fmaxf(h, 0.f);
    o0 += h * W2[jm * 2 + 0];
    o1 += h * W2[jm * 2 + 1];
  }
  out[b * 2 + 0] = o0;
  out[b * 2 + 1] = o1;
}

extern "C" void kernel_launch(void* const* d_in, const int* in_sizes, int n_in,
                              void* d_out, int out_size, void* d_ws,
                              size_t ws_size, hipStream_t stream) {
  const int* node_idx = (const int*)d_in[0];
  const int* ei = (const int*)d_in[1];
  const int* batch = (const int*)d_in[2];
  const float* demo = (const float*)d_in[3];
  const float* emb = (const float*)d_in[4];
  const float* P[24];
  for (int i = 0; i < 24; ++i) P[i] = (const float*)d_in[5 + i];
  const float* W1 = (const float*)d_in[29];
  const float* b1 = (const float*)d_in[30];
  const float* W2 = (const float*)d_in[31];
  const float* b2 = (const float*)d_in[32];

  const size_t NS = (size_t)NN * 96;
  float* X0 = (float*)d_ws;
  float* X1 = X0 + NS;
  float* Q = X0 + 2 * NS;
  float* K = X0 + 3 * NS;
  float* V = X0 + 4 * NS;
  float* DEN = X0 + 5 * NS;       // NN*3 floats
  float* G = DEN + (size_t)NN * 4;  // 64*64 floats

  k_gather<<<(NN * EMB_D + 255) / 256, 256, 0, stream>>>(node_idx, emb, X0);

  // layer 0: FIN=16 HC=96 H=3 C=32  (in X0, skip/out X1, agg reuses X0)
  {
    const float* const* p = &P[0];
    k_qkvs<16, 96><<<(NN + 63) / 64, 256, 0, stream>>>(
        X0, p[0], p[1], p[2], p[3], p[4], p[5], p[6], p[7], Q, K, V, X1);
    hipMemsetAsync(X0, 0, (size_t)NN * 96 * 4, stream);
    hipMemsetAsync(DEN, 0, (size_t)NN * 3 * 4, stream);
    k_edge<3, 32><<<(EE * 3 + 255) / 256, 256, 0, stream>>>(ei, Q, K, V, X0,
                                                            DEN);
    k_fix<3, 32><<<(NN * 96 + 255) / 256, 256, 0, stream>>>(X1, X0, DEN);
  }
  // layer 1: FIN=96 HC=96 H=1 C=96  (in X1, skip/out X0, agg reuses X1)
  {
    const float* const* p = &P[8];
    k_qkvs<96, 96><<<(NN + 63) / 64, 256, 0, stream>>>(
        X1, p[0], p[1], p[2], p[3], p[4], p[5], p[6], p[7], Q, K, V, X0);
    hipMemsetAsync(X1, 0, (size_t)NN * 96 * 4, stream);
    hipMemsetAsync(DEN, 0, (size_t)NN * 1 * 4, stream);
    k_edge<1, 96><<<(EE + 255) / 256, 256, 0, stream>>>(ei, Q, K, V, X1, DEN);
    k_fix<1, 96><<<(NN * 96 + 255) / 256, 256, 0, stream>>>(X0, X1, DEN);
  }
  // layer 2: FIN=96 HC=64 H=1 C=64  (in X0, skip/out X1, agg reuses X0)
  {
    const float* const* p = &P[16];
    k_qkvs<96, 64><<<(NN + 63) / 64, 256, 0, stream>>>(
        X0, p[0], p[1], p[2], p[3], p[4], p[5], p[6], p[7], Q, K, V, X1);
    hipMemsetAsync(X0, 0, (size_t)NN * 64 * 4, stream);
    hipMemsetAsync(DEN, 0, (size_t)NN * 4, stream);
    k_edge<1, 64><<<(EE + 255) / 256, 256, 0, stream>>>(ei, Q, K, V, X0, DEN);
    k_fix<1, 64><<<(NN * 64 + 255) / 256, 256, 0, stream>>>(X1, X0, DEN);
  }

  k_pool<<<BB, 256, 0, stream>>>(X1, batch, G);
  k_mlp<<<1, 64, 0, stream>>>(G, demo, W1, b1, W2, b2, (float*)d_out);
}

// Round 2
// 1160.610 us; speedup vs baseline: 10.1407x; 10.1407x over previous
//
#include <hip/hip_runtime.h>

#define NN 50000
#define EE 800000
#define BB 64
#define EMB_D 16

// ---------------- K0: gather embedding ----------------
__global__ void k_gather(const int* __restrict__ node_idx,
                         const float* __restrict__ emb,
                         float* __restrict__ x) {
  int i = blockIdx.x * blockDim.x + threadIdx.x;
  if (i >= NN * EMB_D) return;
  int n = i >> 4;
  int j = i & 15;
  x[i] = emb[node_idx[n] * EMB_D + j];
}

// ---------------- K1: fused q,k,v,skip GEMMs ----------------
template <int FIN, int HC>
__global__ __launch_bounds__(256) void k_qkvs(
    const float* __restrict__ x, const float* __restrict__ Wq,
    const float* __restrict__ Wk, const float* __restrict__ Wv,
    const float* __restrict__ Ws, const float* __restrict__ bq,
    const float* __restrict__ bk, const float* __restrict__ bv,
    const float* __restrict__ bs, float* __restrict__ q,
    float* __restrict__ k, float* __restrict__ v, float* __restrict__ skip) {
  constexpr int JPG = HC / 4;  // columns per thread
  __shared__ float xs[64 * FIN];
  const int nb = blockIdx.x * 64;
  const int tid = threadIdx.x;
  const int rows = min(64, NN - nb);
  for (int i = tid; i < rows * FIN; i += 256) xs[i] = x[(size_t)nb * FIN + i];
  __syncthreads();
  const int node = tid & 63;
  const int cg = tid >> 6;
  const int j0 = cg * JPG;
  const int n = nb + node;
  if (n >= NN) return;
  const float* W[4] = {Wq, Wk, Wv, Ws};
  const float* bias[4] = {bq, bk, bv, bs};
  float* out[4] = {q, k, v, skip};
#pragma unroll
  for (int m = 0; m < 4; ++m) {
    const float* __restrict__ Wm = W[m];
    float acc[JPG];
#pragma unroll
    for (int j = 0; j < JPG; ++j) acc[j] = bias[m][j0 + j];
    for (int kc = 0; kc < FIN; kc += 16) {
      float xv[16];
#pragma unroll
      for (int kk = 0; kk < 16; ++kk) xv[kk] = xs[node * FIN + kc + kk];
#pragma unroll
      for (int kk = 0; kk < 16; ++kk) {
#pragma unroll
        for (int j = 0; j < JPG; ++j)
          acc[j] += xv[kk] * Wm[(kc + kk) * HC + j0 + j];
      }
    }
    float* o = out[m] + (size_t)n * HC + j0;
#pragma unroll
    for (int j = 0; j < JPG; ++j) o[j] = acc[j];
  }
}

// ---------------- CSR build ----------------
__global__ void k_count(const int* __restrict__ ei, int* __restrict__ counts) {
  int e = blockIdx.x * 256 + threadIdx.x;
  if (e >= EE) return;
  atomicAdd(&counts[ei[EE + e]], 1);
}

// exclusive scan of counts[NN] -> rowptr, 3-kernel (256/block Hillis-Steele)
__global__ void k_scanA(const int* __restrict__ counts, int* __restrict__ excl,
                        int* __restrict__ btot) {
  __shared__ int s[256];
  const int tid = threadIdx.x;
  const int i = blockIdx.x * 256 + tid;
  int v = (i < NN) ? counts[i] : 0;
  s[tid] = v;
  __syncthreads();
  for (int off = 1; off < 256; off <<= 1) {
    int t = (tid >= off) ? s[tid - off] : 0;
    __syncthreads();
    s[tid] += t;
    __syncthreads();
  }
  if (i < NN) excl[i] = s[tid] - v;
  if (tid == 255) btot[blockIdx.x] = s[255];
}

#define NB_SCAN ((NN + 255) / 256)

__global__ void k_scanB(const int* __restrict__ btot, int* __restrict__ boff) {
  __shared__ int s[256];
  const int tid = threadIdx.x;
  int v = (tid < NB_SCAN) ? btot[tid] : 0;
  s[tid] = v;
  __syncthreads();
  for (int off = 1; off < 256; off <<= 1) {
    int t = (tid >= off) ? s[tid - off] : 0;
    __syncthreads();
    s[tid] += t;
    __syncthreads();
  }
  if (tid < NB_SCAN) boff[tid] = s[tid] - v;
}

__global__ void k_scanC(const int* __restrict__ excl,
                        const int* __restrict__ boff,
                        int* __restrict__ rowptr) {
  const int i = blockIdx.x * 256 + threadIdx.x;
  if (i < NN) rowptr[i] = excl[i] + boff[blockIdx.x];
  if (i == 0) rowptr[NN] = EE;
}

__global__ void k_scatter(const int* __restrict__ ei, int* __restrict__ cursor,
                          int* __restrict__ csr_src) {
  int e = blockIdx.x * 256 + threadIdx.x;
  if (e >= EE) return;
  int d = ei[EE + e];
  int p = atomicAdd(&cursor[d], 1);
  csr_src[p] = ei[e];
}

// ---------------- K2: per-(node,head) gather aggregation, no atomics -------
constexpr float scale_of(int c) {
  return c == 32 ? 0.17677669529663687f
                 : (c == 64 ? 0.125f : 0.10206207261596575f);
}

template <int H, int C>
__global__ __launch_bounds__(256) void k_agg(
    const int* __restrict__ rowptr, const int* __restrict__ csr_src,
    const float* __restrict__ q, const float* __restrict__ k,
    const float* __restrict__ v, float* __restrict__ xout) {
  constexpr int HC = H * C;
  constexpr int G = (C == 32) ? 2 : 1;  // edge groups per wave
  constexpr int L = 64 / G;             // lanes per group
  constexpr int CP = (C + L - 1) / L;   // channels per lane
  const int wid = (blockIdx.x * 256 + threadIdx.x) >> 6;
  if (wid >= NN * H) return;
  const int lane = threadIdx.x & 63;
  const int n = wid / H;
  const int h = wid % H;
  const int g = lane / L;
  const int cl = lane % L;
  float qr[CP], acc[CP];
#pragma unroll
  for (int p = 0; p < CP; ++p) {
    int c = cl + p * L;
    qr[p] = (c < C) ? q[(size_t)n * HC + h * C + c] : 0.f;
    acc[p] = 0.f;
  }
  float den = 0.f;
  const int lo = rowptr[n], hi = rowptr[n + 1];
  for (int i = lo + g; i < hi; i += G) {
    const int src = csr_src[i];
    const float* __restrict__ kr = k + (size_t)src * HC + h * C;
    const float* __restrict__ vr = v + (size_t)src * HC + h * C;
    float dot = 0.f;
#pragma unroll
    for (int p = 0; p < CP; ++p) {
      int c = cl + p * L;
      if (c < C) dot += qr[p] * kr[c];
    }
#pragma unroll
    for (int m = L / 2; m >= 1; m >>= 1) dot += __shfl_xor(dot, m);
    const float ea = __expf(dot * scale_of(C));
    den += ea;
#pragma unroll
    for (int p = 0; p < CP; ++p) {
      int c = cl + p * L;
      if (c < C) acc[p] += ea * vr[c];
    }
  }
  if (G == 2) {
    den += __shfl_xor(den, 32);
#pragma unroll
    for (int p = 0; p < CP; ++p) acc[p] += __shfl_xor(acc[p], 32);
  }
  den += 1e-16f;
  if (g == 0) {
#pragma unroll
    for (int p = 0; p < CP; ++p) {
      int c = cl + p * L;
      if (c < C) xout[(size_t)n * HC + h * C + c] += acc[p] / den;
    }
  }
}

// ---------------- K4: segment-mean pool ----------------
__device__ __forceinline__ int lowerb(const int* __restrict__ b, int n,
                                      int key) {
  int lo = 0, hi = n;
  while (lo < hi) {
    int mid = (lo + hi) >> 1;
    if (b[mid] < key) lo = mid + 1;
    else hi = mid;
  }
  return lo;
}

__global__ void k_pool(const float* __restrict__ x,
                       const int* __restrict__ batch, float* __restrict__ g) {
  const int b = blockIdx.x;
  const int lo = lowerb(batch, NN, b);
  const int hi = lowerb(batch, NN, b + 1);
  const int j = threadIdx.x & 63;
  const int r = threadIdx.x >> 6;
  float acc = 0.f;
  for (int n = lo + r; n < hi; n += 4) acc += x[(size_t)n * 64 + j];
  __shared__ float red[256];
  red[threadIdx.x] = acc;
  __syncthreads();
  if (threadIdx.x < 64) {
    float s = red[j] + red[64 + j] + red[128 + j] + red[192 + j];
    int cnt = hi - lo;
    g[b * 64 + j] = s / (float)max(cnt, 1);
  }
}

// ---------------- K5: final MLP ----------------
__global__ void k_mlp(const float* __restrict__ g,
                      const float* __restrict__ demo,
                      const float* __restrict__ W1,
                      const float* __restrict__ b1,
                      const float* __restrict__ W2,
                      const float* __restrict__ b2, float* __restrict__ out) {
  const int b = threadIdx.x;
  if (b >= BB) return;
  float f[69];
#pragma unroll
  for (int t = 0; t < 64; ++t) f[t] = g[b * 64 + t];
#pragma unroll
  for (int t = 0; t < 5; ++t) f[64 + t] = demo[b * 5 + t];
  float o0 = b2[0], o1 = b2[1];
  for (int jm = 0; jm < 32; ++jm) {
    float h = b1[jm];
#pragma unroll
    for (int t = 0; t < 69; ++t) h += f[t] * W1[t * 32 + jm];
    h = fmaxf(h, 0.f);
    o0 += h * W2[jm * 2 + 0];
    o1 += h * W2[jm * 2 + 1];
  }
  out[b * 2 + 0] = o0;
  out[b * 2 + 1] = o1;
}

extern "C" void kernel_launch(void* const* d_in, const int* in_sizes, int n_in,
                              void* d_out, int out_size, void* d_ws,
                              size_t ws_size, hipStream_t stream) {
  const int* node_idx = (const int*)d_in[0];
  const int* ei = (const int*)d_in[1];
  const int* batch = (const int*)d_in[2];
  const float* demo = (const float*)d_in[3];
  const float* emb = (const float*)d_in[4];
  const float* P[24];
  for (int i = 0; i < 24; ++i) P[i] = (const float*)d_in[5 + i];
  const float* W1 = (const float*)d_in[29];
  const float* b1 = (const float*)d_in[30];
  const float* W2 = (const float*)d_in[31];
  const float* b2 = (const float*)d_in[32];

  const size_t NS = (size_t)NN * 96;
  float* X0 = (float*)d_ws;
  float* X1 = X0 + NS;
  float* Q = X0 + 2 * NS;
  float* K = X0 + 3 * NS;
  float* V = X0 + 4 * NS;
  int* counts = (int*)(X0 + 5 * NS);   // NN
  int* excl = counts + NN;             // NN
  int* btot = excl + NN;               // 256
  int* boff = btot + 256;              // 256
  int* rowptr = boff + 256;            // NN+1
  int* cursor = rowptr + NN + 1;       // NN
  int* csr_src = cursor + NN;          // EE
  float* G = (float*)(csr_src + EE);   // 64*64

  // ---- CSR build (dst shared by all layers) ----
  hipMemsetAsync(counts, 0, NN * sizeof(int), stream);
  k_count<<<(EE + 255) / 256, 256, 0, stream>>>(ei, counts);
  k_scanA<<<NB_SCAN, 256, 0, stream>>>(counts, excl, btot);
  k_scanB<<<1, 256, 0, stream>>>(btot, boff);
  k_scanC<<<NB_SCAN, 256, 0, stream>>>(excl, boff, rowptr);
  hipMemcpyAsync(cursor, rowptr, NN * sizeof(int), hipMemcpyDeviceToDevice,
                 stream);
  k_scatter<<<(EE + 255) / 256, 256, 0, stream>>>(ei, cursor, csr_src);

  k_gather<<<(NN * EMB_D + 255) / 256, 256, 0, stream>>>(node_idx, emb, X0);

  // layer 0: FIN=16 HC=96 H=3 C=32  (in X0, skip/out X1)
  {
    const float* const* p = &P[0];
    k_qkvs<16, 96><<<(NN + 63) / 64, 256, 0, stream>>>(
        X0, p[0], p[1], p[2], p[3], p[4], p[5], p[6], p[7], Q, K, V, X1);
    k_agg<3, 32><<<(NN * 3 * 64 + 255) / 256, 256, 0, stream>>>(
        rowptr, csr_src, Q, K, V, X1);
  }
  // layer 1: FIN=96 HC=96 H=1 C=96  (in X1, skip/out X0)
  {
    const float* const* p = &P[8];
    k_qkvs<96, 96><<<(NN + 63) / 64, 256, 0, stream>>>(
        X1, p[0], p[1], p[2], p[3], p[4], p[5], p[6], p[7], Q, K, V, X0);
    k_agg<1, 96><<<(NN * 64 + 255) / 256, 256, 0, stream>>>(
        rowptr, csr_src, Q, K, V, X0);
  }
  // layer 2: FIN=96 HC=64 H=1 C=64  (in X0, skip/out X1)
  {
    const float* const* p = &P[16];
    k_qkvs<96, 64><<<(NN + 63) / 64, 256, 0, stream>>>(
        X0, p[0], p[1], p[2], p[3], p[4], p[5], p[6], p[7], Q, K, V, X1);
    k_agg<1, 64><<<(NN * 64 + 255) / 256, 256, 0, stream>>>(
        rowptr, csr_src, Q, K, V, X1);
  }

  k_pool<<<BB, 256, 0, stream>>>(X1, batch, G);
  k_mlp<<<1, 64, 0, stream>>>(G, demo, W1, b1, W2, b2, (float*)d_out);
}

// Round 3
// 561.865 us; speedup vs baseline: 20.9469x; 2.0656x over previous
//
#include <hip/hip_runtime.h>

#define NN 50000
#define EE 800000
#define BB 64
#define EMB_D 16

// ---------------- K0: gather embedding ----------------
__global__ void k_gather(const int* __restrict__ node_idx,
                         const float* __restrict__ emb,
                         float* __restrict__ x) {
  int i = blockIdx.x * blockDim.x + threadIdx.x;
  if (i >= NN * EMB_D) return;
  int n = i >> 4;
  int j = i & 15;
  x[i] = emb[node_idx[n] * EMB_D + j];
}

// ---------------- K1: fused q,k,v,skip GEMMs ----------------
// 64 nodes x 4 col-groups. xs padded to stride FIN+1: bank=(node+c)%32 ->
// conflict-free. j0 via readfirstlane -> W reads are s_load broadcasts.
template <int FIN, int HC>
__global__ __launch_bounds__(256) void k_qkvs(
    const float* __restrict__ x, const float* __restrict__ Wq,
    const float* __restrict__ Wk, const float* __restrict__ Wv,
    const float* __restrict__ Ws, const float* __restrict__ bq,
    const float* __restrict__ bk, const float* __restrict__ bv,
    const float* __restrict__ bs, float* __restrict__ q,
    float* __restrict__ k, float* __restrict__ v, float* __restrict__ skip) {
  constexpr int JPG = HC / 4;      // columns per thread
  constexpr int STR = FIN + 1;     // padded LDS stride
  __shared__ float xs[64 * STR];
  const int nb = blockIdx.x * 64;
  const int tid = threadIdx.x;
  const int rows = min(64, NN - nb);
  for (int i = tid; i < rows * FIN; i += 256) {
    int nn = i / FIN;
    int cc = i - nn * FIN;
    xs[nn * STR + cc] = x[(size_t)nb * FIN + i];
  }
  __syncthreads();
  const int node = tid & 63;
  const int j0 = __builtin_amdgcn_readfirstlane((tid >> 6) * JPG);
  const int n = nb + node;
  if (n >= NN) return;
  const float* W[4] = {Wq, Wk, Wv, Ws};
  const float* bias[4] = {bq, bk, bv, bs};
  float* out[4] = {q, k, v, skip};
#pragma unroll
  for (int m = 0; m < 4; ++m) {
    const float* __restrict__ Wm = W[m];
    float acc[JPG];
#pragma unroll
    for (int j = 0; j < JPG; ++j) acc[j] = bias[m][j0 + j];
#pragma unroll 4
    for (int kk = 0; kk < FIN; ++kk) {
      const float xv = xs[node * STR + kk];
      const float* __restrict__ Wr = Wm + kk * HC + j0;
#pragma unroll
      for (int j = 0; j < JPG; ++j) acc[j] += xv * Wr[j];
    }
    float* o = out[m] + (size_t)n * HC + j0;
#pragma unroll
    for (int j = 0; j < JPG; ++j) o[j] = acc[j];
  }
}

// ---------------- CSR build ----------------
__global__ void k_count(const int* __restrict__ ei, int* __restrict__ counts) {
  int e = blockIdx.x * 256 + threadIdx.x;
  if (e >= EE) return;
  atomicAdd(&counts[ei[EE + e]], 1);
}

__global__ void k_scanA(const int* __restrict__ counts, int* __restrict__ excl,
                        int* __restrict__ btot) {
  __shared__ int s[256];
  const int tid = threadIdx.x;
  const int i = blockIdx.x * 256 + tid;
  int v = (i < NN) ? counts[i] : 0;
  s[tid] = v;
  __syncthreads();
  for (int off = 1; off < 256; off <<= 1) {
    int t = (tid >= off) ? s[tid - off] : 0;
    __syncthreads();
    s[tid] += t;
    __syncthreads();
  }
  if (i < NN) excl[i] = s[tid] - v;
  if (tid == 255) btot[blockIdx.x] = s[255];
}

#define NB_SCAN ((NN + 255) / 256)

__global__ void k_scanB(const int* __restrict__ btot, int* __restrict__ boff) {
  __shared__ int s[256];
  const int tid = threadIdx.x;
  int v = (tid < NB_SCAN) ? btot[tid] : 0;
  s[tid] = v;
  __syncthreads();
  for (int off = 1; off < 256; off <<= 1) {
    int t = (tid >= off) ? s[tid - off] : 0;
    __syncthreads();
    s[tid] += t;
    __syncthreads();
  }
  if (tid < NB_SCAN) boff[tid] = s[tid] - v;
}

__global__ void k_scanC(const int* __restrict__ excl,
                        const int* __restrict__ boff,
                        int* __restrict__ rowptr) {
  const int i = blockIdx.x * 256 + threadIdx.x;
  if (i < NN) rowptr[i] = excl[i] + boff[blockIdx.x];
  if (i == 0) rowptr[NN] = EE;
}

__global__ void k_scatter(const int* __restrict__ ei, int* __restrict__ cursor,
                          int* __restrict__ csr_src) {
  int e = blockIdx.x * 256 + threadIdx.x;
  if (e >= EE) return;
  int d = ei[EE + e];
  int p = atomicAdd(&cursor[d], 1);
  csr_src[p] = ei[e];
}

// ---------------- K2: gather aggregation, float4 lanes, no atomics --------
constexpr float scale_of(int c) {
  return c == 32 ? 0.17677669529663687f
                 : (c == 64 ? 0.125f : 0.10206207261596575f);
}

// LG lanes per edge-group (8/16/32 for C=32/64/96), G=64/LG edges in flight.
template <int H, int C>
__global__ __launch_bounds__(256) void k_agg(
    const int* __restrict__ rowptr, const int* __restrict__ csr_src,
    const float* __restrict__ q, const float* __restrict__ k,
    const float* __restrict__ v, float* __restrict__ xout) {
  constexpr int HC = H * C;
  constexpr int LQ = C / 4;                 // active float4 lanes per group
  constexpr int LG = (C == 96) ? 32 : LQ;   // lanes per group (pow2)
  constexpr int G = 64 / LG;                // edge groups per wave
  const int wid = (blockIdx.x * 256 + threadIdx.x) >> 6;
  if (wid >= NN * H) return;
  const int lane = threadIdx.x & 63;
  const int n = (H == 1) ? wid : wid / H;
  const int h = (H == 1) ? 0 : wid % H;
  const int g = lane / LG;
  const int cl = lane % LG;
  const bool act = cl < LQ;
  const float* __restrict__ qrow = q + (size_t)n * HC + h * C;
  float4 qr = {0.f, 0.f, 0.f, 0.f};
  if (act) qr = ((const float4*)qrow)[cl];
  float4 acc = {0.f, 0.f, 0.f, 0.f};
  float den = 0.f;
  const int lo = rowptr[n], hi = rowptr[n + 1];
  for (int i = lo + g; i < hi; i += G) {
    const int src = csr_src[i];
    const float* __restrict__ kr = k + (size_t)src * HC + h * C;
    float dot = 0.f;
    if (act) {
      float4 kk = ((const float4*)kr)[cl];
      dot = qr.x * kk.x + qr.y * kk.y + qr.z * kk.z + qr.w * kk.w;
    }
#pragma unroll
    for (int m = LG / 2; m >= 1; m >>= 1) dot += __shfl_xor(dot, m);
    const float ea = __expf(dot * scale_of(C));
    den += ea;
    if (act) {
      const float* __restrict__ vr = v + (size_t)src * HC + h * C;
      float4 vv = ((const float4*)vr)[cl];
      acc.x += ea * vv.x;
      acc.y += ea * vv.y;
      acc.z += ea * vv.z;
      acc.w += ea * vv.w;
    }
  }
#pragma unroll
  for (int m = LG; m < 64; m <<= 1) {
    den += __shfl_xor(den, m);
    acc.x += __shfl_xor(acc.x, m);
    acc.y += __shfl_xor(acc.y, m);
    acc.z += __shfl_xor(acc.z, m);
    acc.w += __shfl_xor(acc.w, m);
  }
  den += 1e-16f;
  if (lane < LQ) {
    float4* o = (float4*)(xout + (size_t)n * HC + h * C);
    float4 cur = o[lane];
    cur.x += acc.x / den;
    cur.y += acc.y / den;
    cur.z += acc.z / den;
    cur.w += acc.w / den;
    o[lane] = cur;
  }
}

// ---------------- K4: segment-mean pool ----------------
__device__ __forceinline__ int lowerb(const int* __restrict__ b, int n,
                                      int key) {
  int lo = 0, hi = n;
  while (lo < hi) {
    int mid = (lo + hi) >> 1;
    if (b[mid] < key) lo = mid + 1;
    else hi = mid;
  }
  return lo;
}

__global__ void k_pool(const float* __restrict__ x,
                       const int* __restrict__ batch, float* __restrict__ g) {
  const int b = blockIdx.x;
  const int lo = lowerb(batch, NN, b);
  const int hi = lowerb(batch, NN, b + 1);
  const int j = threadIdx.x & 63;
  const int r = threadIdx.x >> 6;
  float acc = 0.f;
  for (int n = lo + r; n < hi; n += 4) acc += x[(size_t)n * 64 + j];
  __shared__ float red[256];
  red[threadIdx.x] = acc;
  __syncthreads();
  if (threadIdx.x < 64) {
    float s = red[j] + red[64 + j] + red[128 + j] + red[192 + j];
    int cnt = hi - lo;
    g[b * 64 + j] = s / (float)max(cnt, 1);
  }
}

// ---------------- K5: final MLP ----------------
__global__ void k_mlp(const float* __restrict__ g,
                      const float* __restrict__ demo,
                      const float* __restrict__ W1,
                      const float* __restrict__ b1,
                      const float* __restrict__ W2,
                      const float* __restrict__ b2, float* __restrict__ out) {
  const int b = threadIdx.x;
  if (b >= BB) return;
  float f[69];
#pragma unroll
  for (int t = 0; t < 64; ++t) f[t] = g[b * 64 + t];
#pragma unroll
  for (int t = 0; t < 5; ++t) f[64 + t] = demo[b * 5 + t];
  float o0 = b2[0], o1 = b2[1];
  for (int jm = 0; jm < 32; ++jm) {
    float h = b1[jm];
#pragma unroll
    for (int t = 0; t < 69; ++t) h += f[t] * W1[t * 32 + jm];
    h = fmaxf(h, 0.f);
    o0 += h * W2[jm * 2 + 0];
    o1 += h * W2[jm * 2 + 1];
  }
  out[b * 2 + 0] = o0;
  out[b * 2 + 1] = o1;
}

extern "C" void kernel_launch(void* const* d_in, const int* in_sizes, int n_in,
                              void* d_out, int out_size, void* d_ws,
                              size_t ws_size, hipStream_t stream) {
  const int* node_idx = (const int*)d_in[0];
  const int* ei = (const int*)d_in[1];
  const int* batch = (const int*)d_in[2];
  const float* demo = (const float*)d_in[3];
  const float* emb = (const float*)d_in[4];
  const float* P[24];
  for (int i = 0; i < 24; ++i) P[i] = (const float*)d_in[5 + i];
  const float* W1 = (const float*)d_in[29];
  const float* b1 = (const float*)d_in[30];
  const float* W2 = (const float*)d_in[31];
  const float* b2 = (const float*)d_in[32];

  const size_t NS = (size_t)NN * 96;
  float* X0 = (float*)d_ws;
  float* X1 = X0 + NS;
  float* Q = X0 + 2 * NS;
  float* K = X0 + 3 * NS;
  float* V = X0 + 4 * NS;
  int* counts = (int*)(X0 + 5 * NS);   // NN
  int* excl = counts + NN;             // NN
  int* btot = excl + NN;               // 256
  int* boff = btot + 256;              // 256
  int* rowptr = boff + 256;            // NN+1
  int* cursor = rowptr + NN + 1;       // NN
  int* csr_src = cursor + NN;          // EE
  float* G = (float*)(csr_src + EE);   // 64*64

  // ---- CSR build (dst shared by all layers) ----
  hipMemsetAsync(counts, 0, NN * sizeof(int), stream);
  k_count<<<(EE + 255) / 256, 256, 0, stream>>>(ei, counts);
  k_scanA<<<NB_SCAN, 256, 0, stream>>>(counts, excl, btot);
  k_scanB<<<1, 256, 0, stream>>>(btot, boff);
  k_scanC<<<NB_SCAN, 256, 0, stream>>>(excl, boff, rowptr);
  hipMemcpyAsync(cursor, rowptr, NN * sizeof(int), hipMemcpyDeviceToDevice,
                 stream);
  k_scatter<<<(EE + 255) / 256, 256, 0, stream>>>(ei, cursor, csr_src);

  k_gather<<<(NN * EMB_D + 255) / 256, 256, 0, stream>>>(node_idx, emb, X0);

  // layer 0: FIN=16 HC=96 H=3 C=32  (in X0, skip/out X1)
  {
    const float* const* p = &P[0];
    k_qkvs<16, 96><<<(NN + 63) / 64, 256, 0, stream>>>(
        X0, p[0], p[1], p[2], p[3], p[4], p[5], p[6], p[7], Q, K, V, X1);
    k_agg<3, 32><<<(NN * 3 * 64 + 255) / 256, 256, 0, stream>>>(
        rowptr, csr_src, Q, K, V, X1);
  }
  // layer 1: FIN=96 HC=96 H=1 C=96  (in X1, skip/out X0)
  {
    const float* const* p = &P[8];
    k_qkvs<96, 96><<<(NN + 63) / 64, 256, 0, stream>>>(
        X1, p[0], p[1], p[2], p[3], p[4], p[5], p[6], p[7], Q, K, V, X0);
    k_agg<1, 96><<<(NN * 64 + 255) / 256, 256, 0, stream>>>(
        rowptr, csr_src, Q, K, V, X0);
  }
  // layer 2: FIN=96 HC=64 H=1 C=64  (in X0, skip/out X1)
  {
    const float* const* p = &P[16];
    k_qkvs<96, 64><<<(NN + 63) / 64, 256, 0, stream>>>(
        X0, p[0], p[1], p[2], p[3], p[4], p[5], p[6], p[7], Q, K, V, X1);
    k_agg<1, 64><<<(NN * 64 + 255) / 256, 256, 0, stream>>>(
        rowptr, csr_src, Q, K, V, X1);
  }

  k_pool<<<BB, 256, 0, stream>>>(X1, batch, G);
  k_mlp<<<1, 64, 0, stream>>>(G, demo, W1, b1, W2, b2, (float*)d_out);
}

// Round 4
// 484.696 us; speedup vs baseline: 24.2819x; 1.1592x over previous
//
#include <hip/hip_runtime.h>
#include <hip/hip_bf16.h>

#define NN 50000
#define EE 800000
#define BB 64
#define EMB_D 16

typedef unsigned short u16;
struct u16x4 { u16 x, y, z, w; };

__device__ __forceinline__ float b2f(u16 u) {
  union { unsigned int i; float f; } c;
  c.i = ((unsigned int)u) << 16;
  return c.f;
}

// ---------------- K0: gather embedding ----------------
__global__ void k_gather(const int* __restrict__ node_idx,
                         const float* __restrict__ emb,
                         float* __restrict__ x) {
  int i = blockIdx.x * blockDim.x + threadIdx.x;
  if (i >= NN * EMB_D) return;
  int n = i >> 4;
  int j = i & 15;
  x[i] = emb[node_idx[n] * EMB_D + j];
}

// ---------------- K1: fused q,k,v,skip GEMMs (k,v out in bf16) ------------
template <int FIN, int HC>
__global__ __launch_bounds__(256) void k_qkvs(
    const float* __restrict__ x, const float* __restrict__ Wq,
    const float* __restrict__ Wk, const float* __restrict__ Wv,
    const float* __restrict__ Ws, const float* __restrict__ bq,
    const float* __restrict__ bk, const float* __restrict__ bv,
    const float* __restrict__ bs, float* __restrict__ q,
    __hip_bfloat16* __restrict__ k, __hip_bfloat16* __restrict__ v,
    float* __restrict__ skip) {
  constexpr int JPG = HC / 4;      // columns per thread
  constexpr int STR = FIN + 1;     // padded LDS stride
  __shared__ float xs[64 * STR];
  const int nb = blockIdx.x * 64;
  const int tid = threadIdx.x;
  const int rows = min(64, NN - nb);
  for (int i = tid; i < rows * FIN; i += 256) {
    int nn = i / FIN;
    int cc = i - nn * FIN;
    xs[nn * STR + cc] = x[(size_t)nb * FIN + i];
  }
  __syncthreads();
  const int node = tid & 63;
  const int j0 = __builtin_amdgcn_readfirstlane((tid >> 6) * JPG);
  const int n = nb + node;
  if (n >= NN) return;
  const float* W[4] = {Wq, Wk, Wv, Ws};
  const float* bias[4] = {bq, bk, bv, bs};
#pragma unroll
  for (int m = 0; m < 4; ++m) {
    const float* __restrict__ Wm = W[m];
    float acc[JPG];
#pragma unroll
    for (int j = 0; j < JPG; ++j) acc[j] = bias[m][j0 + j];
#pragma unroll 4
    for (int kk = 0; kk < FIN; ++kk) {
      const float xv = xs[node * STR + kk];
      const float* __restrict__ Wr = Wm + kk * HC + j0;
#pragma unroll
      for (int j = 0; j < JPG; ++j) acc[j] += xv * Wr[j];
    }
    if (m == 1 || m == 2) {
      __hip_bfloat16* o = (m == 1 ? k : v) + (size_t)n * HC + j0;
#pragma unroll
      for (int j = 0; j < JPG; ++j) o[j] = __float2bfloat16(acc[j]);
    } else {
      float* o = (m == 0 ? q : skip) + (size_t)n * HC + j0;
#pragma unroll
      for (int j = 0; j < JPG; ++j) o[j] = acc[j];
    }
  }
}

// ---------------- CSR build ----------------
__global__ void k_count(const int* __restrict__ ei, int* __restrict__ counts) {
  int e = blockIdx.x * 256 + threadIdx.x;
  if (e >= EE) return;
  atomicAdd(&counts[ei[EE + e]], 1);
}

__global__ void k_scanA(const int* __restrict__ counts, int* __restrict__ excl,
                        int* __restrict__ btot) {
  __shared__ int s[256];
  const int tid = threadIdx.x;
  const int i = blockIdx.x * 256 + tid;
  int v = (i < NN) ? counts[i] : 0;
  s[tid] = v;
  __syncthreads();
  for (int off = 1; off < 256; off <<= 1) {
    int t = (tid >= off) ? s[tid - off] : 0;
    __syncthreads();
    s[tid] += t;
    __syncthreads();
  }
  if (i < NN) excl[i] = s[tid] - v;
  if (tid == 255) btot[blockIdx.x] = s[255];
}

#define NB_SCAN ((NN + 255) / 256)

__global__ void k_scanB(const int* __restrict__ btot, int* __restrict__ boff) {
  __shared__ int s[256];
  const int tid = threadIdx.x;
  int v = (tid < NB_SCAN) ? btot[tid] : 0;
  s[tid] = v;
  __syncthreads();
  for (int off = 1; off < 256; off <<= 1) {
    int t = (tid >= off) ? s[tid - off] : 0;
    __syncthreads();
    s[tid] += t;
    __syncthreads();
  }
  if (tid < NB_SCAN) boff[tid] = s[tid] - v;
}

__global__ void k_scanC(const int* __restrict__ excl,
                        const int* __restrict__ boff,
                        int* __restrict__ rowptr) {
  const int i = blockIdx.x * 256 + threadIdx.x;
  if (i < NN) rowptr[i] = excl[i] + boff[blockIdx.x];
  if (i == 0) rowptr[NN] = EE;
}

__global__ void k_scatter(const int* __restrict__ ei, int* __restrict__ cursor,
                          int* __restrict__ csr_src) {
  int e = blockIdx.x * 256 + threadIdx.x;
  if (e >= EE) return;
  int d = ei[EE + e];
  int p = atomicAdd(&cursor[d], 1);
  csr_src[p] = ei[e];
}

// ---------------- K2: gather aggregation, bf16 k/v, 2x unrolled -----------
constexpr float scale_of(int c) {
  return c == 32 ? 0.17677669529663687f
                 : (c == 64 ? 0.125f : 0.10206207261596575f);
}

template <int H, int C>
__global__ __launch_bounds__(256) void k_agg(
    const int* __restrict__ rowptr, const int* __restrict__ csr_src,
    const float* __restrict__ q, const __hip_bfloat16* __restrict__ k,
    const __hip_bfloat16* __restrict__ v, float* __restrict__ xout) {
  constexpr int HC = H * C;
  constexpr int LQ = C / 4;                 // active lanes per group (4ch ea)
  constexpr int LG = (C == 96) ? 32 : LQ;   // lanes per group (pow2)
  constexpr int G = 64 / LG;                // edge groups per wave
  const int wid = (blockIdx.x * 256 + threadIdx.x) >> 6;
  if (wid >= NN * H) return;
  const int lane = threadIdx.x & 63;
  const int n = (H == 1) ? wid : wid / H;
  const int h = (H == 1) ? 0 : wid % H;
  const int g = lane / LG;
  const int cl = lane % LG;
  const bool act = cl < LQ;
  const float* __restrict__ qrow = q + (size_t)n * HC + h * C;
  float4 qr = {0.f, 0.f, 0.f, 0.f};
  if (act) qr = ((const float4*)qrow)[cl];
  const u16* __restrict__ kb = (const u16*)k + h * C;
  const u16* __restrict__ vb = (const u16*)v + h * C;
  float4 acc = {0.f, 0.f, 0.f, 0.f};
  float den = 0.f;
  const int lo = rowptr[n], hi = rowptr[n + 1];
  int i = lo + g;
  for (; i + G < hi; i += 2 * G) {
    const int s0 = csr_src[i];
    const int s1 = csr_src[i + G];
    u16x4 k0 = {0, 0, 0, 0}, k1 = {0, 0, 0, 0};
    u16x4 v0 = {0, 0, 0, 0}, v1 = {0, 0, 0, 0};
    if (act) {
      k0 = ((const u16x4*)(kb + (size_t)s0 * HC))[cl];
      v0 = ((const u16x4*)(vb + (size_t)s0 * HC))[cl];
      k1 = ((const u16x4*)(kb + (size_t)s1 * HC))[cl];
      v1 = ((const u16x4*)(vb + (size_t)s1 * HC))[cl];
    }
    float d0 = qr.x * b2f(k0.x) + qr.y * b2f(k0.y) + qr.z * b2f(k0.z) +
               qr.w * b2f(k0.w);
    float d1 = qr.x * b2f(k1.x) + qr.y * b2f(k1.y) + qr.z * b2f(k1.z) +
               qr.w * b2f(k1.w);
#pragma unroll
    for (int m = LG / 2; m >= 1; m >>= 1) {
      d0 += __shfl_xor(d0, m);
      d1 += __shfl_xor(d1, m);
    }
    const float e0 = __expf(d0 * scale_of(C));
    const float e1 = __expf(d1 * scale_of(C));
    den += e0 + e1;
    acc.x += e0 * b2f(v0.x) + e1 * b2f(v1.x);
    acc.y += e0 * b2f(v0.y) + e1 * b2f(v1.y);
    acc.z += e0 * b2f(v0.z) + e1 * b2f(v1.z);
    acc.w += e0 * b2f(v0.w) + e1 * b2f(v1.w);
  }
  if (i < hi) {
    const int s0 = csr_src[i];
    u16x4 k0 = {0, 0, 0, 0}, v0 = {0, 0, 0, 0};
    if (act) {
      k0 = ((const u16x4*)(kb + (size_t)s0 * HC))[cl];
      v0 = ((const u16x4*)(vb + (size_t)s0 * HC))[cl];
    }
    float d0 = qr.x * b2f(k0.x) + qr.y * b2f(k0.y) + qr.z * b2f(k0.z) +
               qr.w * b2f(k0.w);
#pragma unroll
    for (int m = LG / 2; m >= 1; m >>= 1) d0 += __shfl_xor(d0, m);
    const float e0 = __expf(d0 * scale_of(C));
    den += e0;
    acc.x += e0 * b2f(v0.x);
    acc.y += e0 * b2f(v0.y);
    acc.z += e0 * b2f(v0.z);
    acc.w += e0 * b2f(v0.w);
  }
#pragma unroll
  for (int m = LG; m < 64; m <<= 1) {
    den += __shfl_xor(den, m);
    acc.x += __shfl_xor(acc.x, m);
    acc.y += __shfl_xor(acc.y, m);
    acc.z += __shfl_xor(acc.z, m);
    acc.w += __shfl_xor(acc.w, m);
  }
  den += 1e-16f;
  if (lane < LQ) {
    float4* o = (float4*)(xout + (size_t)n * HC + h * C);
    float4 cur = o[lane];
    cur.x += acc.x / den;
    cur.y += acc.y / den;
    cur.z += acc.z / den;
    cur.w += acc.w / den;
    o[lane] = cur;
  }
}

// ---------------- K4: segment-mean pool ----------------
__device__ __forceinline__ int lowerb(const int* __restrict__ b, int n,
                                      int key) {
  int lo = 0, hi = n;
  while (lo < hi) {
    int mid = (lo + hi) >> 1;
    if (b[mid] < key) lo = mid + 1;
    else hi = mid;
  }
  return lo;
}

__global__ void k_pool(const float* __restrict__ x,
                       const int* __restrict__ batch, float* __restrict__ g) {
  const int b = blockIdx.x;
  const int lo = lowerb(batch, NN, b);
  const int hi = lowerb(batch, NN, b + 1);
  const int j = threadIdx.x & 63;
  const int r = threadIdx.x >> 6;
  float acc = 0.f;
  for (int n = lo + r; n < hi; n += 4) acc += x[(size_t)n * 64 + j];
  __shared__ float red[256];
  red[threadIdx.x] = acc;
  __syncthreads();
  if (threadIdx.x < 64) {
    float s = red[j] + red[64 + j] + red[128 + j] + red[192 + j];
    int cnt = hi - lo;
    g[b * 64 + j] = s / (float)max(cnt, 1);
  }
}

// ---------------- K5: final MLP ----------------
__global__ void k_mlp(const float* __restrict__ g,
                      const float* __restrict__ demo,
                      const float* __restrict__ W1,
                      const float* __restrict__ b1,
                      const float* __restrict__ W2,
                      const float* __restrict__ b2, float* __restrict__ out) {
  const int b = threadIdx.x;
  if (b >= BB) return;
  float f[69];
#pragma unroll
  for (int t = 0; t < 64; ++t) f[t] = g[b * 64 + t];
#pragma unroll
  for (int t = 0; t < 5; ++t) f[64 + t] = demo[b * 5 + t];
  float o0 = b2[0], o1 = b2[1];
  for (int jm = 0; jm < 32; ++jm) {
    float h = b1[jm];
#pragma unroll
    for (int t = 0; t < 69; ++t) h += f[t] * W1[t * 32 + jm];
    h = fmaxf(h, 0.f);
    o0 += h * W2[jm * 2 + 0];
    o1 += h * W2[jm * 2 + 1];
  }
  out[b * 2 + 0] = o0;
  out[b * 2 + 1] = o1;
}

extern "C" void kernel_launch(void* const* d_in, const int* in_sizes, int n_in,
                              void* d_out, int out_size, void* d_ws,
                              size_t ws_size, hipStream_t stream) {
  const int* node_idx = (const int*)d_in[0];
  const int* ei = (const int*)d_in[1];
  const int* batch = (const int*)d_in[2];
  const float* demo = (const float*)d_in[3];
  const float* emb = (const float*)d_in[4];
  const float* P[24];
  for (int i = 0; i < 24; ++i) P[i] = (const float*)d_in[5 + i];
  const float* W1 = (const float*)d_in[29];
  const float* b1 = (const float*)d_in[30];
  const float* W2 = (const float*)d_in[31];
  const float* b2 = (const float*)d_in[32];

  const size_t NS = (size_t)NN * 96;
  float* X0 = (float*)d_ws;
  float* X1 = X0 + NS;
  float* Q = X0 + 2 * NS;
  __hip_bfloat16* K = (__hip_bfloat16*)(X0 + 3 * NS);
  __hip_bfloat16* V = (__hip_bfloat16*)(X0 + 4 * NS);
  int* counts = (int*)(X0 + 5 * NS);   // NN
  int* excl = counts + NN;             // NN
  int* btot = excl + NN;               // 256
  int* boff = btot + 256;              // 256
  int* rowptr = boff + 256;            // NN+1
  int* cursor = rowptr + NN + 1;       // NN
  int* csr_src = cursor + NN;          // EE
  float* G = (float*)(csr_src + EE);   // 64*64

  // ---- CSR build (dst shared by all layers) ----
  hipMemsetAsync(counts, 0, NN * sizeof(int), stream);
  k_count<<<(EE + 255) / 256, 256, 0, stream>>>(ei, counts);
  k_scanA<<<NB_SCAN, 256, 0, stream>>>(counts, excl, btot);
  k_scanB<<<1, 256, 0, stream>>>(btot, boff);
  k_scanC<<<NB_SCAN, 256, 0, stream>>>(excl, boff, rowptr);
  hipMemcpyAsync(cursor, rowptr, NN * sizeof(int), hipMemcpyDeviceToDevice,
                 stream);
  k_scatter<<<(EE + 255) / 256, 256, 0, stream>>>(ei, cursor, csr_src);

  k_gather<<<(NN * EMB_D + 255) / 256, 256, 0, stream>>>(node_idx, emb, X0);

  // layer 0: FIN=16 HC=96 H=3 C=32  (in X0, skip/out X1)
  {
    const float* const* p = &P[0];
    k_qkvs<16, 96><<<(NN + 63) / 64, 256, 0, stream>>>(
        X0, p[0], p[1], p[2], p[3], p[4], p[5], p[6], p[7], Q, K, V, X1);
    k_agg<3, 32><<<(NN * 3 * 64 + 255) / 256, 256, 0, stream>>>(
        rowptr, csr_src, Q, K, V, X1);
  }
  // layer 1: FIN=96 HC=96 H=1 C=96  (in X1, skip/out X0)
  {
    const float* const* p = &P[8];
    k_qkvs<96, 96><<<(NN + 63) / 64, 256, 0, stream>>>(
        X1, p[0], p[1], p[2], p[3], p[4], p[5], p[6], p[7], Q, K, V, X0);
    k_agg<1, 96><<<(NN * 64 + 255) / 256, 256, 0, stream>>>(
        rowptr, csr_src, Q, K, V, X0);
  }
  // layer 2: FIN=96 HC=64 H=1 C=64  (in X0, skip/out X1)
  {
    const float* const* p = &P[16];
    k_qkvs<96, 64><<<(NN + 63) / 64, 256, 0, stream>>>(
        X0, p[0], p[1], p[2], p[3], p[4], p[5], p[6], p[7], Q, K, V, X1);
    k_agg<1, 64><<<(NN * 64 + 255) / 256, 256, 0, stream>>>(
        rowptr, csr_src, Q, K, V, X1);
  }

  k_pool<<<BB, 256, 0, stream>>>(X1, batch, G);
  k_mlp<<<1, 64, 0, stream>>>(G, demo, W1, b1, W2, b2, (float*)d_out);
}

// Round 5
// 482.670 us; speedup vs baseline: 24.3838x; 1.0042x over previous
//
#include <hip/hip_runtime.h>
#include <hip/hip_bf16.h>

#define NN 50000
#define EE 800000
#define BB 64
#define EMB_D 16

typedef unsigned short u16;

__device__ __forceinline__ float blo(unsigned u) {
  union { unsigned i; float f; } c;
  c.i = u << 16;
  return c.f;
}
__device__ __forceinline__ float bhi(unsigned u) {
  union { unsigned i; float f; } c;
  c.i = u & 0xffff0000u;
  return c.f;
}

// ---------------- K0: gather embedding ----------------
__global__ void k_gather(const int* __restrict__ node_idx,
                         const float* __restrict__ emb,
                         float* __restrict__ x) {
  int i = blockIdx.x * blockDim.x + threadIdx.x;
  if (i >= NN * EMB_D) return;
  int n = i >> 4;
  int j = i & 15;
  x[i] = emb[node_idx[n] * EMB_D + j];
}

// ---------------- K1: q,k,v,skip GEMMs; blockIdx.y selects matrix ---------
template <int FIN, int HC>
__global__ __launch_bounds__(256) void k_qkvs(
    const float* __restrict__ x, const float* __restrict__ Wq,
    const float* __restrict__ Wk, const float* __restrict__ Wv,
    const float* __restrict__ Ws, const float* __restrict__ bq,
    const float* __restrict__ bk, const float* __restrict__ bv,
    const float* __restrict__ bs, float* __restrict__ q,
    __hip_bfloat16* __restrict__ k, __hip_bfloat16* __restrict__ v,
    float* __restrict__ skip) {
  constexpr int JPG = HC / 4;      // columns per thread
  constexpr int STR = FIN + 1;     // padded LDS stride
  __shared__ float xs[64 * STR];
  const int nb = blockIdx.x * 64;
  const int m = blockIdx.y;        // 0=q 1=k 2=v 3=skip
  const int tid = threadIdx.x;
  const int rows = min(64, NN - nb);
  for (int i = tid; i < rows * FIN; i += 256) {
    int nn = i / FIN;
    int cc = i - nn * FIN;
    xs[nn * STR + cc] = x[(size_t)nb * FIN + i];
  }
  __syncthreads();
  const int node = tid & 63;
  const int j0 = __builtin_amdgcn_readfirstlane((tid >> 6) * JPG);
  const int n = nb + node;
  if (n >= NN) return;
  const float* __restrict__ Wm = (m == 0) ? Wq : (m == 1) ? Wk : (m == 2) ? Wv : Ws;
  const float* __restrict__ bm = (m == 0) ? bq : (m == 1) ? bk : (m == 2) ? bv : bs;
  float acc[JPG];
#pragma unroll
  for (int j = 0; j < JPG; ++j) acc[j] = bm[j0 + j];
#pragma unroll 4
  for (int kk = 0; kk < FIN; ++kk) {
    const float xv = xs[node * STR + kk];
    const float* __restrict__ Wr = Wm + kk * HC + j0;
#pragma unroll
    for (int j = 0; j < JPG; ++j) acc[j] += xv * Wr[j];
  }
  if (m == 1 || m == 2) {
    __hip_bfloat16* o = (m == 1 ? k : v) + (size_t)n * HC + j0;
#pragma unroll
    for (int j = 0; j < JPG; ++j) o[j] = __float2bfloat16(acc[j]);
  } else {
    float* o = (m == 0 ? q : skip) + (size_t)n * HC + j0;
#pragma unroll
    for (int j = 0; j < JPG; ++j) o[j] = acc[j];
  }
}

// ---------------- CSR build ----------------
__global__ void k_count(const int* __restrict__ ei, int* __restrict__ counts) {
  int e = blockIdx.x * 256 + threadIdx.x;
  if (e >= EE) return;
  atomicAdd(&counts[ei[EE + e]], 1);
}

__global__ void k_scanA(const int* __restrict__ counts, int* __restrict__ excl,
                        int* __restrict__ btot) {
  __shared__ int s[256];
  const int tid = threadIdx.x;
  const int i = blockIdx.x * 256 + tid;
  int v = (i < NN) ? counts[i] : 0;
  s[tid] = v;
  __syncthreads();
  for (int off = 1; off < 256; off <<= 1) {
    int t = (tid >= off) ? s[tid - off] : 0;
    __syncthreads();
    s[tid] += t;
    __syncthreads();
  }
  if (i < NN) excl[i] = s[tid] - v;
  if (tid == 255) btot[blockIdx.x] = s[255];
}

#define NB_SCAN ((NN + 255) / 256)

__global__ void k_scanB(const int* __restrict__ btot, int* __restrict__ boff) {
  __shared__ int s[256];
  const int tid = threadIdx.x;
  int v = (tid < NB_SCAN) ? btot[tid] : 0;
  s[tid] = v;
  __syncthreads();
  for (int off = 1; off < 256; off <<= 1) {
    int t = (tid >= off) ? s[tid - off] : 0;
    __syncthreads();
    s[tid] += t;
    __syncthreads();
  }
  if (tid < NB_SCAN) boff[tid] = s[tid] - v;
}

__global__ void k_scanC(const int* __restrict__ excl,
                        const int* __restrict__ boff,
                        int* __restrict__ rowptr) {
  const int i = blockIdx.x * 256 + threadIdx.x;
  if (i < NN) rowptr[i] = excl[i] + boff[blockIdx.x];
  if (i == 0) rowptr[NN] = EE;
}

__global__ void k_scatter(const int* __restrict__ ei, int* __restrict__ cursor,
                          int* __restrict__ csr_src) {
  int e = blockIdx.x * 256 + threadIdx.x;
  if (e >= EE) return;
  int d = ei[EE + e];
  int p = atomicAdd(&cursor[d], 1);
  csr_src[p] = ei[e];
}

// ---------------- K2: gather aggregation, bf16 u16x8 lanes ----------------
constexpr float scale_of(int c) {
  return c == 32 ? 0.17677669529663687f
                 : (c == 64 ? 0.125f : 0.10206207261596575f);
}

__device__ __forceinline__ float dot8(float4 a, float4 b, uint4 u) {
  return a.x * blo(u.x) + a.y * bhi(u.x) + a.z * blo(u.y) + a.w * bhi(u.y) +
         b.x * blo(u.z) + b.y * bhi(u.z) + b.z * blo(u.w) + b.w * bhi(u.w);
}

template <int H, int C>
__global__ __launch_bounds__(256) void k_agg(
    const int* __restrict__ rowptr, const int* __restrict__ csr_src,
    const float* __restrict__ q, const __hip_bfloat16* __restrict__ k,
    const __hip_bfloat16* __restrict__ v, float* __restrict__ xout) {
  constexpr int HC = H * C;
  constexpr int LQ = C / 8;                 // active lanes (8 ch each)
  constexpr int LG = (C == 96) ? 16 : LQ;   // lanes per group (pow2)
  constexpr int G = 64 / LG;                // edge groups per wave
  const int wid = (blockIdx.x * 256 + threadIdx.x) >> 6;
  if (wid >= NN * H) return;
  const int lane = threadIdx.x & 63;
  const int n = (H == 1) ? wid : wid / H;
  const int h = (H == 1) ? 0 : wid % H;
  const int g = lane / LG;
  const int cl = lane % LG;
  const bool act = cl < LQ;
  const float4* __restrict__ q4 = (const float4*)(q + (size_t)n * HC + h * C);
  float4 qA = {0.f, 0.f, 0.f, 0.f}, qB = {0.f, 0.f, 0.f, 0.f};
  if (act) {
    qA = q4[cl * 2];
    qB = q4[cl * 2 + 1];
  }
  const u16* __restrict__ kb = (const u16*)k + h * C;
  const u16* __restrict__ vb = (const u16*)v + h * C;
  const unsigned coff = (unsigned)cl * 8;
  float4 aA = {0.f, 0.f, 0.f, 0.f}, aB = {0.f, 0.f, 0.f, 0.f};
  float den = 0.f;
  const int lo = rowptr[n], hi = rowptr[n + 1];
  int i = lo + g;
  for (; i + G < hi; i += 2 * G) {
    const int s0 = csr_src[i];
    const int s1 = csr_src[i + G];
    const unsigned o0 = (unsigned)s0 * HC + coff;
    const unsigned o1 = (unsigned)s1 * HC + coff;
    uint4 k0 = {0, 0, 0, 0}, k1 = {0, 0, 0, 0};
    uint4 v0 = {0, 0, 0, 0}, v1 = {0, 0, 0, 0};
    if (act) {
      k0 = *(const uint4*)(kb + (size_t)o0);
      v0 = *(const uint4*)(vb + (size_t)o0);
      k1 = *(const uint4*)(kb + (size_t)o1);
      v1 = *(const uint4*)(vb + (size_t)o1);
    }
    float d0 = dot8(qA, qB, k0);
    float d1 = dot8(qA, qB, k1);
#pragma unroll
    for (int m = LG / 2; m >= 1; m >>= 1) {
      d0 += __shfl_xor(d0, m);
      d1 += __shfl_xor(d1, m);
    }
    const float e0 = __expf(d0 * scale_of(C));
    const float e1 = __expf(d1 * scale_of(C));
    den += e0 + e1;
    aA.x += e0 * blo(v0.x) + e1 * blo(v1.x);
    aA.y += e0 * bhi(v0.x) + e1 * bhi(v1.x);
    aA.z += e0 * blo(v0.y) + e1 * blo(v1.y);
    aA.w += e0 * bhi(v0.y) + e1 * bhi(v1.y);
    aB.x += e0 * blo(v0.z) + e1 * blo(v1.z);
    aB.y += e0 * bhi(v0.z) + e1 * bhi(v1.z);
    aB.z += e0 * blo(v0.w) + e1 * blo(v1.w);
    aB.w += e0 * bhi(v0.w) + e1 * bhi(v1.w);
  }
  if (i < hi) {
    const int s0 = csr_src[i];
    const unsigned o0 = (unsigned)s0 * HC + coff;
    uint4 k0 = {0, 0, 0, 0}, v0 = {0, 0, 0, 0};
    if (act) {
      k0 = *(const uint4*)(kb + (size_t)o0);
      v0 = *(const uint4*)(vb + (size_t)o0);
    }
    float d0 = dot8(qA, qB, k0);
#pragma unroll
    for (int m = LG / 2; m >= 1; m >>= 1) d0 += __shfl_xor(d0, m);
    const float e0 = __expf(d0 * scale_of(C));
    den += e0;
    aA.x += e0 * blo(v0.x);
    aA.y += e0 * bhi(v0.x);
    aA.z += e0 * blo(v0.y);
    aA.w += e0 * bhi(v0.y);
    aB.x += e0 * blo(v0.z);
    aB.y += e0 * bhi(v0.z);
    aB.z += e0 * blo(v0.w);
    aB.w += e0 * bhi(v0.w);
  }
#pragma unroll
  for (int m = LG; m < 64; m <<= 1) {
    den += __shfl_xor(den, m);
    aA.x += __shfl_xor(aA.x, m);
    aA.y += __shfl_xor(aA.y, m);
    aA.z += __shfl_xor(aA.z, m);
    aA.w += __shfl_xor(aA.w, m);
    aB.x += __shfl_xor(aB.x, m);
    aB.y += __shfl_xor(aB.y, m);
    aB.z += __shfl_xor(aB.z, m);
    aB.w += __shfl_xor(aB.w, m);
  }
  den += 1e-16f;
  if (lane < LQ) {
    float4* o = (float4*)(xout + (size_t)n * HC + h * C);
    float4 c0 = o[lane * 2];
    float4 c1 = o[lane * 2 + 1];
    c0.x += aA.x / den;
    c0.y += aA.y / den;
    c0.z += aA.z / den;
    c0.w += aA.w / den;
    c1.x += aB.x / den;
    c1.y += aB.y / den;
    c1.z += aB.z / den;
    c1.w += aB.w / den;
    o[lane * 2] = c0;
    o[lane * 2 + 1] = c1;
  }
}

// ---------------- K4: segment-mean pool ----------------
__device__ __forceinline__ int lowerb(const int* __restrict__ b, int n,
                                      int key) {
  int lo = 0, hi = n;
  while (lo < hi) {
    int mid = (lo + hi) >> 1;
    if (b[mid] < key) lo = mid + 1;
    else hi = mid;
  }
  return lo;
}

__global__ void k_pool(const float* __restrict__ x,
                       const int* __restrict__ batch, float* __restrict__ g) {
  const int b = blockIdx.x;
  const int lo = lowerb(batch, NN, b);
  const int hi = lowerb(batch, NN, b + 1);
  const int j = threadIdx.x & 63;
  const int r = threadIdx.x >> 6;
  float acc = 0.f;
  for (int n = lo + r; n < hi; n += 4) acc += x[(size_t)n * 64 + j];
  __shared__ float red[256];
  red[threadIdx.x] = acc;
  __syncthreads();
  if (threadIdx.x < 64) {
    float s = red[j] + red[64 + j] + red[128 + j] + red[192 + j];
    int cnt = hi - lo;
    g[b * 64 + j] = s / (float)max(cnt, 1);
  }
}

// ---------------- K5: final MLP ----------------
__global__ void k_mlp(const float* __restrict__ g,
                      const float* __restrict__ demo,
                      const float* __restrict__ W1,
                      const float* __restrict__ b1,
                      const float* __restrict__ W2,
                      const float* __restrict__ b2, float* __restrict__ out) {
  const int b = threadIdx.x;
  if (b >= BB) return;
  float f[69];
#pragma unroll
  for (int t = 0; t < 64; ++t) f[t] = g[b * 64 + t];
#pragma unroll
  for (int t = 0; t < 5; ++t) f[64 + t] = demo[b * 5 + t];
  float o0 = b2[0], o1 = b2[1];
  for (int jm = 0; jm < 32; ++jm) {
    float h = b1[jm];
#pragma unroll
    for (int t = 0; t < 69; ++t) h += f[t] * W1[t * 32 + jm];
    h = fmaxf(h, 0.f);
    o0 += h * W2[jm * 2 + 0];
    o1 += h * W2[jm * 2 + 1];
  }
  out[b * 2 + 0] = o0;
  out[b * 2 + 1] = o1;
}

extern "C" void kernel_launch(void* const* d_in, const int* in_sizes, int n_in,
                              void* d_out, int out_size, void* d_ws,
                              size_t ws_size, hipStream_t stream) {
  const int* node_idx = (const int*)d_in[0];
  const int* ei = (const int*)d_in[1];
  const int* batch = (const int*)d_in[2];
  const float* demo = (const float*)d_in[3];
  const float* emb = (const float*)d_in[4];
  const float* P[24];
  for (int i = 0; i < 24; ++i) P[i] = (const float*)d_in[5 + i];
  const float* W1 = (const float*)d_in[29];
  const float* b1 = (const float*)d_in[30];
  const float* W2 = (const float*)d_in[31];
  const float* b2 = (const float*)d_in[32];

  const size_t NS = (size_t)NN * 96;
  float* X0 = (float*)d_ws;
  float* X1 = X0 + NS;
  float* Q = X0 + 2 * NS;
  __hip_bfloat16* K = (__hip_bfloat16*)(X0 + 3 * NS);
  __hip_bfloat16* V = (__hip_bfloat16*)(X0 + 4 * NS);
  int* counts = (int*)(X0 + 5 * NS);   // NN
  int* excl = counts + NN;             // NN
  int* btot = excl + NN;               // 256
  int* boff = btot + 256;              // 256
  int* rowptr = boff + 256;            // NN+1
  int* cursor = rowptr + NN + 1;       // NN
  int* csr_src = cursor + NN;          // EE
  float* G = (float*)(csr_src + EE);   // 64*64

  // ---- CSR build (dst shared by all layers) ----
  hipMemsetAsync(counts, 0, NN * sizeof(int), stream);
  k_count<<<(EE + 255) / 256, 256, 0, stream>>>(ei, counts);
  k_scanA<<<NB_SCAN, 256, 0, stream>>>(counts, excl, btot);
  k_scanB<<<1, 256, 0, stream>>>(btot, boff);
  k_scanC<<<NB_SCAN, 256, 0, stream>>>(excl, boff, rowptr);
  hipMemcpyAsync(cursor, rowptr, NN * sizeof(int), hipMemcpyDeviceToDevice,
                 stream);
  k_scatter<<<(EE + 255) / 256, 256, 0, stream>>>(ei, cursor, csr_src);

  k_gather<<<(NN * EMB_D + 255) / 256, 256, 0, stream>>>(node_idx, emb, X0);

  const dim3 gq((NN + 63) / 64, 4);
  // layer 0: FIN=16 HC=96 H=3 C=32  (in X0, skip/out X1)
  {
    const float* const* p = &P[0];
    k_qkvs<16, 96><<<gq, 256, 0, stream>>>(
        X0, p[0], p[1], p[2], p[3], p[4], p[5], p[6], p[7], Q, K, V, X1);
    k_agg<3, 32><<<(NN * 3 * 64 + 255) / 256, 256, 0, stream>>>(
        rowptr, csr_src, Q, K, V, X1);
  }
  // layer 1: FIN=96 HC=96 H=1 C=96  (in X1, skip/out X0)
  {
    const float* const* p = &P[8];
    k_qkvs<96, 96><<<gq, 256, 0, stream>>>(
        X1, p[0], p[1], p[2], p[3], p[4], p[5], p[6], p[7], Q, K, V, X0);
    k_agg<1, 96><<<(NN * 64 + 255) / 256, 256, 0, stream>>>(
        rowptr, csr_src, Q, K, V, X0);
  }
  // layer 2: FIN=96 HC=64 H=1 C=64  (in X0, skip/out X1)
  {
    const float* const* p = &P[16];
    k_qkvs<96, 64><<<gq, 256, 0, stream>>>(
        X0, p[0], p[1], p[2], p[3], p[4], p[5], p[6], p[7], Q, K, V, X1);
    k_agg<1, 64><<<(NN * 64 + 255) / 256, 256, 0, stream>>>(
        rowptr, csr_src, Q, K, V, X1);
  }

  k_pool<<<BB, 256, 0, stream>>>(X1, batch, G);
  k_mlp<<<1, 64, 0, stream>>>(G, demo, W1, b1, W2, b2, (float*)d_out);
}

// Round 6
// 427.717 us; speedup vs baseline: 27.5167x; 1.1285x over previous
//
#include <hip/hip_runtime.h>

#define NN 50000
#define EE 800000
#define BB 64

typedef float fx2 __attribute__((ext_vector_type(2)));

// ---------------- K1: q,k,v,skip GEMMs; blockIdx.y selects matrix ---------
// K,V outputs packed fp8 e4m3 into interleaved KV rows [K(HC) | V(HC)].
template <int FIN, int HC, bool EMB>
__global__ __launch_bounds__(256) void k_qkvs(
    const float* __restrict__ x, const int* __restrict__ node_idx,
    const float* __restrict__ emb, const float* __restrict__ Wq,
    const float* __restrict__ Wk, const float* __restrict__ Wv,
    const float* __restrict__ Ws, const float* __restrict__ bq,
    const float* __restrict__ bk, const float* __restrict__ bv,
    const float* __restrict__ bs, float* __restrict__ q,
    unsigned char* __restrict__ kv, float* __restrict__ skip) {
  constexpr int JPG = HC / 4;      // columns per thread
  constexpr int STR = FIN + 1;     // padded LDS stride
  __shared__ float xs[64 * STR];
  const int nb = blockIdx.x * 64;
  const int m = blockIdx.y;        // 0=q 1=k 2=v 3=skip
  const int tid = threadIdx.x;
  const int rows = min(64, NN - nb);
  if (EMB) {
    for (int i = tid; i < rows * 16; i += 256) {
      int nn = i >> 4, cc = i & 15;
      xs[nn * STR + cc] = emb[node_idx[nb + nn] * 16 + cc];
    }
  } else {
    for (int i = tid; i < rows * FIN; i += 256) {
      int nn = i / FIN, cc = i - nn * FIN;
      xs[nn * STR + cc] = x[(size_t)nb * FIN + i];
    }
  }
  __syncthreads();
  const int node = tid & 63;
  const int j0 = __builtin_amdgcn_readfirstlane((tid >> 6) * JPG);
  const int n = nb + node;
  if (n >= NN) return;
  const float* __restrict__ Wm = (m == 0) ? Wq : (m == 1) ? Wk : (m == 2) ? Wv : Ws;
  const float* __restrict__ bm = (m == 0) ? bq : (m == 1) ? bk : (m == 2) ? bv : bs;
  float acc[JPG];
#pragma unroll
  for (int j = 0; j < JPG; ++j) acc[j] = bm[j0 + j];
#pragma unroll 4
  for (int kk = 0; kk < FIN; ++kk) {
    const float xv = xs[node * STR + kk];
    const float* __restrict__ Wr = Wm + kk * HC + j0;
#pragma unroll
    for (int j = 0; j < JPG; ++j) acc[j] += xv * Wr[j];
  }
  if (m == 1 || m == 2) {
    unsigned char* o = kv + (size_t)n * (2 * HC) + (m == 2 ? HC : 0) + j0;
#pragma unroll
    for (int j = 0; j < JPG; j += 4) {
      int w = 0;
      w = __builtin_amdgcn_cvt_pk_fp8_f32(acc[j], acc[j + 1], w, false);
      w = __builtin_amdgcn_cvt_pk_fp8_f32(acc[j + 2], acc[j + 3], w, true);
      *(int*)(o + j) = w;
    }
  } else {
    float* o = (m == 0 ? q : skip) + (size_t)n * HC + j0;
#pragma unroll
    for (int j = 0; j < JPG; ++j) o[j] = acc[j];
  }
}

// ---------------- CSR build ----------------
__global__ void k_count(const int* __restrict__ ei, int* __restrict__ counts) {
  int e = blockIdx.x * 256 + threadIdx.x;
  if (e >= EE) return;
  atomicAdd(&counts[ei[EE + e]], 1);
}

__global__ void k_scanA(const int* __restrict__ counts, int* __restrict__ excl,
                        int* __restrict__ btot) {
  __shared__ int s[256];
  const int tid = threadIdx.x;
  const int i = blockIdx.x * 256 + tid;
  int v = (i < NN) ? counts[i] : 0;
  s[tid] = v;
  __syncthreads();
  for (int off = 1; off < 256; off <<= 1) {
    int t = (tid >= off) ? s[tid - off] : 0;
    __syncthreads();
    s[tid] += t;
    __syncthreads();
  }
  if (i < NN) excl[i] = s[tid] - v;
  if (tid == 255) btot[blockIdx.x] = s[255];
}

#define NB_SCAN ((NN + 255) / 256)

__global__ void k_scanB(const int* __restrict__ btot, int* __restrict__ boff) {
  __shared__ int s[256];
  const int tid = threadIdx.x;
  int v = (tid < NB_SCAN) ? btot[tid] : 0;
  s[tid] = v;
  __syncthreads();
  for (int off = 1; off < 256; off <<= 1) {
    int t = (tid >= off) ? s[tid - off] : 0;
    __syncthreads();
    s[tid] += t;
    __syncthreads();
  }
  if (tid < NB_SCAN) boff[tid] = s[tid] - v;
}

__global__ void k_scanC(const int* __restrict__ excl,
                        const int* __restrict__ boff,
                        int* __restrict__ rowptr, int* __restrict__ cursor) {
  const int i = blockIdx.x * 256 + threadIdx.x;
  if (i < NN) {
    int r = excl[i] + boff[blockIdx.x];
    rowptr[i] = r;
    cursor[i] = r;
  }
  if (i == 0) rowptr[NN] = EE;
}

__global__ void k_scatter(const int* __restrict__ ei, int* __restrict__ cursor,
                          int* __restrict__ csr_src) {
  int e = blockIdx.x * 256 + threadIdx.x;
  if (e >= EE) return;
  int d = ei[EE + e];
  int p = atomicAdd(&cursor[d], 1);
  csr_src[p] = ei[e];
}

// ---------------- K2: merged-head gather aggregation, fp8 KV --------------
constexpr float scale_of(int c) {
  return c == 32 ? 0.17677669529663687f
                 : (c == 64 ? 0.125f : 0.10206207261596575f);
}

// One wave per NODE. Group = full HC row (ROW=HC/4 active lanes, 4 ch each).
// G = 64/LG edge groups in flight. Segmented shfl reduce per head.
template <int H, int C>
__global__ __launch_bounds__(256) void k_agg(
    const int* __restrict__ rowptr, const int* __restrict__ csr_src,
    const float* __restrict__ q, const unsigned char* __restrict__ kv,
    float* __restrict__ xout) {
  constexpr int HC = H * C;
  constexpr int ROW = HC / 4;               // active lanes per group
  constexpr int LG = (ROW > 16) ? 32 : 16;  // group width (pow2)
  constexpr int G = 64 / LG;                // edge groups per wave
  constexpr int RW = (H == 1) ? LG : 8;     // dot-reduce width (seg per head)
  const int n = blockIdx.x * (256 / 64) + (threadIdx.x >> 6);
  if (n >= NN) return;
  const int lane = threadIdx.x & 63;
  const int g = lane / LG;
  const int cl = lane % LG;
  const bool act = cl < ROW;
  float4 qr = {0.f, 0.f, 0.f, 0.f};
  if (act) qr = ((const float4*)(q + (size_t)n * HC))[cl];
  const unsigned coff = 4u * (unsigned)cl;
  float4 acc = {0.f, 0.f, 0.f, 0.f};
  float den = 0.f;
  const int lo = rowptr[n], hi = rowptr[n + 1];
  int i = lo + g;
  for (; i + G < hi; i += 2 * G) {
    const int s0 = csr_src[i];
    const int s1 = csr_src[i + G];
    const unsigned char* r0 = kv + (size_t)((unsigned)s0 * (2 * HC));
    const unsigned char* r1 = kv + (size_t)((unsigned)s1 * (2 * HC));
    int kw0 = 0, vw0 = 0, kw1 = 0, vw1 = 0;
    if (act) {
      kw0 = *(const int*)(r0 + coff);
      vw0 = *(const int*)(r0 + HC + coff);
      kw1 = *(const int*)(r1 + coff);
      vw1 = *(const int*)(r1 + HC + coff);
    }
    fx2 a0 = __builtin_amdgcn_cvt_pk_f32_fp8(kw0, false);
    fx2 b0 = __builtin_amdgcn_cvt_pk_f32_fp8(kw0, true);
    fx2 a1 = __builtin_amdgcn_cvt_pk_f32_fp8(kw1, false);
    fx2 b1 = __builtin_amdgcn_cvt_pk_f32_fp8(kw1, true);
    float d0 = qr.x * a0.x + qr.y * a0.y + qr.z * b0.x + qr.w * b0.y;
    float d1 = qr.x * a1.x + qr.y * a1.y + qr.z * b1.x + qr.w * b1.y;
#pragma unroll
    for (int m = 1; m < RW; m <<= 1) {
      d0 += __shfl_xor(d0, m);
      d1 += __shfl_xor(d1, m);
    }
    const float e0 = __expf(d0 * scale_of(C));
    const float e1 = __expf(d1 * scale_of(C));
    den += e0 + e1;
    fx2 va0 = __builtin_amdgcn_cvt_pk_f32_fp8(vw0, false);
    fx2 vb0 = __builtin_amdgcn_cvt_pk_f32_fp8(vw0, true);
    fx2 va1 = __builtin_amdgcn_cvt_pk_f32_fp8(vw1, false);
    fx2 vb1 = __builtin_amdgcn_cvt_pk_f32_fp8(vw1, true);
    acc.x += e0 * va0.x + e1 * va1.x;
    acc.y += e0 * va0.y + e1 * va1.y;
    acc.z += e0 * vb0.x + e1 * vb1.x;
    acc.w += e0 * vb0.y + e1 * vb1.y;
  }
  if (i < hi) {
    const int s0 = csr_src[i];
    const unsigned char* r0 = kv + (size_t)((unsigned)s0 * (2 * HC));
    int kw0 = 0, vw0 = 0;
    if (act) {
      kw0 = *(const int*)(r0 + coff);
      vw0 = *(const int*)(r0 + HC + coff);
    }
    fx2 a0 = __builtin_amdgcn_cvt_pk_f32_fp8(kw0, false);
    fx2 b0 = __builtin_amdgcn_cvt_pk_f32_fp8(kw0, true);
    float d0 = qr.x * a0.x + qr.y * a0.y + qr.z * b0.x + qr.w * b0.y;
#pragma unroll
    for (int m = 1; m < RW; m <<= 1) d0 += __shfl_xor(d0, m);
    const float e0 = __expf(d0 * scale_of(C));
    den += e0;
    fx2 va0 = __builtin_amdgcn_cvt_pk_f32_fp8(vw0, false);
    fx2 vb0 = __builtin_amdgcn_cvt_pk_f32_fp8(vw0, true);
    acc.x += e0 * va0.x;
    acc.y += e0 * va0.y;
    acc.z += e0 * vb0.x;
    acc.w += e0 * vb0.y;
  }
#pragma unroll
  for (int m = LG; m < 64; m <<= 1) {
    den += __shfl_xor(den, m);
    acc.x += __shfl_xor(acc.x, m);
    acc.y += __shfl_xor(acc.y, m);
    acc.z += __shfl_xor(acc.z, m);
    acc.w += __shfl_xor(acc.w, m);
  }
  if (lane < ROW) {
    const float inv = 1.f / (den + 1e-16f);
    float4* o = (float4*)(xout + (size_t)n * HC);
    float4 c = o[lane];
    c.x += acc.x * inv;
    c.y += acc.y * inv;
    c.z += acc.z * inv;
    c.w += acc.w * inv;
    o[lane] = c;
  }
}

// ---------------- K4: segment-mean pool ----------------
__device__ __forceinline__ int lowerb(const int* __restrict__ b, int n,
                                      int key) {
  int lo = 0, hi = n;
  while (lo < hi) {
    int mid = (lo + hi) >> 1;
    if (b[mid] < key) lo = mid + 1;
    else hi = mid;
  }
  return lo;
}

__global__ void k_pool(const float* __restrict__ x,
                       const int* __restrict__ batch, float* __restrict__ g) {
  const int b = blockIdx.x;
  const int lo = lowerb(batch, NN, b);
  const int hi = lowerb(batch, NN, b + 1);
  const int j = threadIdx.x & 63;
  const int r = threadIdx.x >> 6;
  float acc = 0.f;
  for (int n = lo + r; n < hi; n += 4) acc += x[(size_t)n * 64 + j];
  __shared__ float red[256];
  red[threadIdx.x] = acc;
  __syncthreads();
  if (threadIdx.x < 64) {
    float s = red[j] + red[64 + j] + red[128 + j] + red[192 + j];
    int cnt = hi - lo;
    g[b * 64 + j] = s / (float)max(cnt, 1);
  }
}

// ---------------- K5: final MLP ----------------
__global__ void k_mlp(const float* __restrict__ g,
                      const float* __restrict__ demo,
                      const float* __restrict__ W1,
                      const float* __restrict__ b1,
                      const float* __restrict__ W2,
                      const float* __restrict__ b2, float* __restrict__ out) {
  const int b = threadIdx.x;
  if (b >= BB) return;
  float f[69];
#pragma unroll
  for (int t = 0; t < 64; ++t) f[t] = g[b * 64 + t];
#pragma unroll
  for (int t = 0; t < 5; ++t) f[64 + t] = demo[b * 5 + t];
  float o0 = b2[0], o1 = b2[1];
  for (int jm = 0; jm < 32; ++jm) {
    float h = b1[jm];
#pragma unroll
    for (int t = 0; t < 69; ++t) h += f[t] * W1[t * 32 + jm];
    h = fmaxf(h, 0.f);
    o0 += h * W2[jm * 2 + 0];
    o1 += h * W2[jm * 2 + 1];
  }
  out[b * 2 + 0] = o0;
  out[b * 2 + 1] = o1;
}

extern "C" void kernel_launch(void* const* d_in, const int* in_sizes, int n_in,
                              void* d_out, int out_size, void* d_ws,
                              size_t ws_size, hipStream_t stream) {
  const int* node_idx = (const int*)d_in[0];
  const int* ei = (const int*)d_in[1];
  const int* batch = (const int*)d_in[2];
  const float* demo = (const float*)d_in[3];
  const float* emb = (const float*)d_in[4];
  const float* P[24];
  for (int i = 0; i < 24; ++i) P[i] = (const float*)d_in[5 + i];
  const float* W1 = (const float*)d_in[29];
  const float* b1 = (const float*)d_in[30];
  const float* W2 = (const float*)d_in[31];
  const float* b2 = (const float*)d_in[32];

  const size_t NS = (size_t)NN * 96;
  float* X0 = (float*)d_ws;
  float* X1 = X0 + NS;
  float* Q = X0 + 2 * NS;
  unsigned char* KV = (unsigned char*)(X0 + 3 * NS);  // NN*192 bytes
  int* counts = (int*)(X0 + 3 * NS + NS / 2);  // NN
  int* excl = counts + NN;                     // NN
  int* btot = excl + NN;                       // 256
  int* boff = btot + 256;                      // 256
  int* rowptr = boff + 256;                    // NN+1
  int* cursor = rowptr + NN + 1;               // NN
  int* csr_src = cursor + NN;                  // EE
  float* G = (float*)(csr_src + EE);           // 64*64

  // ---- CSR build (dst shared by all layers) ----
  hipMemsetAsync(counts, 0, NN * sizeof(int), stream);
  k_count<<<(EE + 255) / 256, 256, 0, stream>>>(ei, counts);
  k_scanA<<<NB_SCAN, 256, 0, stream>>>(counts, excl, btot);
  k_scanB<<<1, 256, 0, stream>>>(btot, boff);
  k_scanC<<<NB_SCAN, 256, 0, stream>>>(excl, boff, rowptr, cursor);
  k_scatter<<<(EE + 255) / 256, 256, 0, stream>>>(ei, cursor, csr_src);

  const dim3 gq((NN + 63) / 64, 4);
  const int nwb = (NN * 64 + 255) / 256;  // one wave per node
  // layer 0: FIN=16 HC=96 H=3 C=32  (emb-fused in, skip/out X1)
  {
    const float* const* p = &P[0];
    k_qkvs<16, 96, true><<<gq, 256, 0, stream>>>(
        nullptr, node_idx, emb, p[0], p[1], p[2], p[3], p[4], p[5], p[6], p[7],
        Q, KV, X1);
    k_agg<3, 32><<<nwb, 256, 0, stream>>>(rowptr, csr_src, Q, KV, X1);
  }
  // layer 1: FIN=96 HC=96 H=1 C=96  (in X1, skip/out X0)
  {
    const float* const* p = &P[8];
    k_qkvs<96, 96, false><<<gq, 256, 0, stream>>>(
        X1, nullptr, nullptr, p[0], p[1], p[2], p[3], p[4], p[5], p[6], p[7],
        Q, KV, X0);
    k_agg<1, 96><<<nwb, 256, 0, stream>>>(rowptr, csr_src, Q, KV, X0);
  }
  // layer 2: FIN=96 HC=64 H=1 C=64  (in X0, skip/out X1)
  {
    const float* const* p = &P[16];
    k_qkvs<96, 64, false><<<gq, 256, 0, stream>>>(
        X0, nullptr, nullptr, p[0], p[1], p[2], p[3], p[4], p[5], p[6], p[7],
        Q, KV, X1);
    k_agg<1, 64><<<nwb, 256, 0, stream>>>(rowptr, csr_src, Q, KV, X1);
  }

  k_pool<<<BB, 256, 0, stream>>>(X1, batch, G);
  k_mlp<<<1, 64, 0, stream>>>(G, demo, W1, b1, W2, b2, (float*)d_out);
}

// Round 7
// 421.683 us; speedup vs baseline: 27.9104x; 1.0143x over previous
//
#include <hip/hip_runtime.h>

#define NN 50000
#define EE 800000
#define BB 64

typedef float fx2 __attribute__((ext_vector_type(2)));

// ---------------- K1: q,k,v,skip GEMMs; blockIdx.y selects matrix ---------
// No LDS: x rows read directly as float4 (L1/L2-resident; vmcnt counter),
// W rows via scalar s_loads (lgkmcnt) -> counters decoupled, SMEM pipelines.
// K,V outputs packed fp8 e4m3 into interleaved KV rows [K(HC) | V(HC)].
template <int FIN, int HC, bool EMB>
__global__ __launch_bounds__(256) void k_qkvs(
    const float* __restrict__ x, const int* __restrict__ node_idx,
    const float* __restrict__ emb, const float* __restrict__ Wq,
    const float* __restrict__ Wk, const float* __restrict__ Wv,
    const float* __restrict__ Ws, const float* __restrict__ bq,
    const float* __restrict__ bk, const float* __restrict__ bv,
    const float* __restrict__ bs, float* __restrict__ q,
    unsigned char* __restrict__ kv, float* __restrict__ skip) {
  constexpr int JPG = HC / 4;      // columns per thread
  const int nb = blockIdx.x * 64;
  const int m = blockIdx.y;        // 0=q 1=k 2=v 3=skip
  const int node = threadIdx.x & 63;
  const int j0 = __builtin_amdgcn_readfirstlane((threadIdx.x >> 6) * JPG);
  const int n = nb + node;
  if (n >= NN) return;
  const float* __restrict__ xr =
      EMB ? emb + (size_t)node_idx[n] * 16 : x + (size_t)n * FIN;
  const float* __restrict__ Wm = (m == 0) ? Wq : (m == 1) ? Wk : (m == 2) ? Wv : Ws;
  const float* __restrict__ bm = (m == 0) ? bq : (m == 1) ? bk : (m == 2) ? bv : bs;
  float acc[JPG];
#pragma unroll
  for (int j = 0; j < JPG; ++j) acc[j] = bm[j0 + j];
#pragma unroll 4
  for (int kk = 0; kk < FIN; kk += 4) {
    const float4 xv = *(const float4*)(xr + kk);
#pragma unroll
    for (int t = 0; t < 4; ++t) {
      const float xsv = (t == 0) ? xv.x : (t == 1) ? xv.y : (t == 2) ? xv.z : xv.w;
      const float* __restrict__ Wr = Wm + (kk + t) * HC + j0;
#pragma unroll
      for (int j = 0; j < JPG; ++j) acc[j] += xsv * Wr[j];
    }
  }
  if (m == 1 || m == 2) {
    unsigned char* o = kv + (size_t)n * (2 * HC) + (m == 2 ? HC : 0) + j0;
#pragma unroll
    for (int j = 0; j < JPG; j += 4) {
      int w = 0;
      w = __builtin_amdgcn_cvt_pk_fp8_f32(acc[j], acc[j + 1], w, false);
      w = __builtin_amdgcn_cvt_pk_fp8_f32(acc[j + 2], acc[j + 3], w, true);
      *(int*)(o + j) = w;
    }
  } else {
    float* o = (m == 0 ? q : skip) + (size_t)n * HC + j0;
#pragma unroll
    for (int j = 0; j < JPG; ++j) o[j] = acc[j];
  }
}

// ---------------- CSR build ----------------
__global__ void k_count(const int* __restrict__ ei, int* __restrict__ counts) {
  int e = blockIdx.x * 256 + threadIdx.x;
  if (e >= EE) return;
  atomicAdd(&counts[ei[EE + e]], 1);
}

__global__ void k_scanA(const int* __restrict__ counts, int* __restrict__ excl,
                        int* __restrict__ btot) {
  __shared__ int s[256];
  const int tid = threadIdx.x;
  const int i = blockIdx.x * 256 + tid;
  int v = (i < NN) ? counts[i] : 0;
  s[tid] = v;
  __syncthreads();
  for (int off = 1; off < 256; off <<= 1) {
    int t = (tid >= off) ? s[tid - off] : 0;
    __syncthreads();
    s[tid] += t;
    __syncthreads();
  }
  if (i < NN) excl[i] = s[tid] - v;
  if (tid == 255) btot[blockIdx.x] = s[255];
}

#define NB_SCAN ((NN + 255) / 256)

__global__ void k_scanB(const int* __restrict__ btot, int* __restrict__ boff) {
  __shared__ int s[256];
  const int tid = threadIdx.x;
  int v = (tid < NB_SCAN) ? btot[tid] : 0;
  s[tid] = v;
  __syncthreads();
  for (int off = 1; off < 256; off <<= 1) {
    int t = (tid >= off) ? s[tid - off] : 0;
    __syncthreads();
    s[tid] += t;
    __syncthreads();
  }
  if (tid < NB_SCAN) boff[tid] = s[tid] - v;
}

__global__ void k_scanC(const int* __restrict__ excl,
                        const int* __restrict__ boff,
                        int* __restrict__ rowptr, int* __restrict__ cursor) {
  const int i = blockIdx.x * 256 + threadIdx.x;
  if (i < NN) {
    int r = excl[i] + boff[blockIdx.x];
    rowptr[i] = r;
    cursor[i] = r;
  }
  if (i == 0) rowptr[NN] = EE;
}

__global__ void k_scatter(const int* __restrict__ ei, int* __restrict__ cursor,
                          int* __restrict__ csr_src) {
  int e = blockIdx.x * 256 + threadIdx.x;
  if (e >= EE) return;
  int d = ei[EE + e];
  int p = atomicAdd(&cursor[d], 1);
  csr_src[p] = ei[e];
}

// ---------------- K2: merged-head gather aggregation, fp8 KV --------------
constexpr float scale_of(int c) {
  return c == 32 ? 0.17677669529663687f
                 : (c == 64 ? 0.125f : 0.10206207261596575f);
}

// One wave per NODE. Group = full HC row (ROW=HC/4 active lanes, 4 ch each).
// G = 64/LG edge groups in flight. Segmented shfl reduce per head.
template <int H, int C>
__global__ __launch_bounds__(256) void k_agg(
    const int* __restrict__ rowptr, const int* __restrict__ csr_src,
    const float* __restrict__ q, const unsigned char* __restrict__ kv,
    float* __restrict__ xout) {
  constexpr int HC = H * C;
  constexpr int ROW = HC / 4;               // active lanes per group
  constexpr int LG = (ROW > 16) ? 32 : 16;  // group width (pow2)
  constexpr int G = 64 / LG;                // edge groups per wave
  constexpr int RW = (H == 1) ? LG : 8;     // dot-reduce width (seg per head)
  const int n = blockIdx.x * (256 / 64) + (threadIdx.x >> 6);
  if (n >= NN) return;
  const int lane = threadIdx.x & 63;
  const int g = lane / LG;
  const int cl = lane % LG;
  const bool act = cl < ROW;
  float4 qr = {0.f, 0.f, 0.f, 0.f};
  if (act) qr = ((const float4*)(q + (size_t)n * HC))[cl];
  const unsigned coff = 4u * (unsigned)cl;
  float4 acc = {0.f, 0.f, 0.f, 0.f};
  float den = 0.f;
  const int lo = rowptr[n], hi = rowptr[n + 1];
  int i = lo + g;
  for (; i + G < hi; i += 2 * G) {
    const int s0 = csr_src[i];
    const int s1 = csr_src[i + G];
    const unsigned char* r0 = kv + (size_t)((unsigned)s0 * (2 * HC));
    const unsigned char* r1 = kv + (size_t)((unsigned)s1 * (2 * HC));
    int kw0 = 0, vw0 = 0, kw1 = 0, vw1 = 0;
    if (act) {
      kw0 = *(const int*)(r0 + coff);
      vw0 = *(const int*)(r0 + HC + coff);
      kw1 = *(const int*)(r1 + coff);
      vw1 = *(const int*)(r1 + HC + coff);
    }
    fx2 a0 = __builtin_amdgcn_cvt_pk_f32_fp8(kw0, false);
    fx2 b0 = __builtin_amdgcn_cvt_pk_f32_fp8(kw0, true);
    fx2 a1 = __builtin_amdgcn_cvt_pk_f32_fp8(kw1, false);
    fx2 b1 = __builtin_amdgcn_cvt_pk_f32_fp8(kw1, true);
    float d0 = qr.x * a0.x + qr.y * a0.y + qr.z * b0.x + qr.w * b0.y;
    float d1 = qr.x * a1.x + qr.y * a1.y + qr.z * b1.x + qr.w * b1.y;
#pragma unroll
    for (int m = 1; m < RW; m <<= 1) {
      d0 += __shfl_xor(d0, m);
      d1 += __shfl_xor(d1, m);
    }
    const float e0 = __expf(d0 * scale_of(C));
    const float e1 = __expf(d1 * scale_of(C));
    den += e0 + e1;
    fx2 va0 = __builtin_amdgcn_cvt_pk_f32_fp8(vw0, false);
    fx2 vb0 = __builtin_amdgcn_cvt_pk_f32_fp8(vw0, true);
    fx2 va1 = __builtin_amdgcn_cvt_pk_f32_fp8(vw1, false);
    fx2 vb1 = __builtin_amdgcn_cvt_pk_f32_fp8(vw1, true);
    acc.x += e0 * va0.x + e1 * va1.x;
    acc.y += e0 * va0.y + e1 * va1.y;
    acc.z += e0 * vb0.x + e1 * vb1.x;
    acc.w += e0 * vb0.y + e1 * vb1.y;
  }
  if (i < hi) {
    const int s0 = csr_src[i];
    const unsigned char* r0 = kv + (size_t)((unsigned)s0 * (2 * HC));
    int kw0 = 0, vw0 = 0;
    if (act) {
      kw0 = *(const int*)(r0 + coff);
      vw0 = *(const int*)(r0 + HC + coff);
    }
    fx2 a0 = __builtin_amdgcn_cvt_pk_f32_fp8(kw0, false);
    fx2 b0 = __builtin_amdgcn_cvt_pk_f32_fp8(kw0, true);
    float d0 = qr.x * a0.x + qr.y * a0.y + qr.z * b0.x + qr.w * b0.y;
#pragma unroll
    for (int m = 1; m < RW; m <<= 1) d0 += __shfl_xor(d0, m);
    const float e0 = __expf(d0 * scale_of(C));
    den += e0;
    fx2 va0 = __builtin_amdgcn_cvt_pk_f32_fp8(vw0, false);
    fx2 vb0 = __builtin_amdgcn_cvt_pk_f32_fp8(vw0, true);
    acc.x += e0 * va0.x;
    acc.y += e0 * va0.y;
    acc.z += e0 * vb0.x;
    acc.w += e0 * vb0.y;
  }
#pragma unroll
  for (int m = LG; m < 64; m <<= 1) {
    den += __shfl_xor(den, m);
    acc.x += __shfl_xor(acc.x, m);
    acc.y += __shfl_xor(acc.y, m);
    acc.z += __shfl_xor(acc.z, m);
    acc.w += __shfl_xor(acc.w, m);
  }
  if (lane < ROW) {
    const float inv = 1.f / (den + 1e-16f);
    float4* o = (float4*)(xout + (size_t)n * HC);
    float4 c = o[lane];
    c.x += acc.x * inv;
    c.y += acc.y * inv;
    c.z += acc.z * inv;
    c.w += acc.w * inv;
    o[lane] = c;
  }
}

// ---------------- K4: segment-mean pool ----------------
__device__ __forceinline__ int lowerb(const int* __restrict__ b, int n,
                                      int key) {
  int lo = 0, hi = n;
  while (lo < hi) {
    int mid = (lo + hi) >> 1;
    if (b[mid] < key) lo = mid + 1;
    else hi = mid;
  }
  return lo;
}

__global__ void k_pool(const float* __restrict__ x,
                       const int* __restrict__ batch, float* __restrict__ g) {
  const int b = blockIdx.x;
  const int lo = lowerb(batch, NN, b);
  const int hi = lowerb(batch, NN, b + 1);
  const int j = threadIdx.x & 63;
  const int r = threadIdx.x >> 6;
  float acc = 0.f;
  for (int n = lo + r; n < hi; n += 4) acc += x[(size_t)n * 64 + j];
  __shared__ float red[256];
  red[threadIdx.x] = acc;
  __syncthreads();
  if (threadIdx.x < 64) {
    float s = red[j] + red[64 + j] + red[128 + j] + red[192 + j];
    int cnt = hi - lo;
    g[b * 64 + j] = s / (float)max(cnt, 1);
  }
}

// ---------------- K5: final MLP ----------------
__global__ void k_mlp(const float* __restrict__ g,
                      const float* __restrict__ demo,
                      const float* __restrict__ W1,
                      const float* __restrict__ b1,
                      const float* __restrict__ W2,
                      const float* __restrict__ b2, float* __restrict__ out) {
  const int b = threadIdx.x;
  if (b >= BB) return;
  float f[69];
#pragma unroll
  for (int t = 0; t < 64; ++t) f[t] = g[b * 64 + t];
#pragma unroll
  for (int t = 0; t < 5; ++t) f[64 + t] = demo[b * 5 + t];
  float o0 = b2[0], o1 = b2[1];
  for (int jm = 0; jm < 32; ++jm) {
    float h = b1[jm];
#pragma unroll
    for (int t = 0; t < 69; ++t) h += f[t] * W1[t * 32 + jm];
    h = fmaxf(h, 0.f);
    o0 += h * W2[jm * 2 + 0];
    o1 += h * W2[jm * 2 + 1];
  }
  out[b * 2 + 0] = o0;
  out[b * 2 + 1] = o1;
}

extern "C" void kernel_launch(void* const* d_in, const int* in_sizes, int n_in,
                              void* d_out, int out_size, void* d_ws,
                              size_t ws_size, hipStream_t stream) {
  const int* node_idx = (const int*)d_in[0];
  const int* ei = (const int*)d_in[1];
  const int* batch = (const int*)d_in[2];
  const float* demo = (const float*)d_in[3];
  const float* emb = (const float*)d_in[4];
  const float* P[24];
  for (int i = 0; i < 24; ++i) P[i] = (const float*)d_in[5 + i];
  const float* W1 = (const float*)d_in[29];
  const float* b1 = (const float*)d_in[30];
  const float* W2 = (const float*)d_in[31];
  const float* b2 = (const float*)d_in[32];

  const size_t NS = (size_t)NN * 96;
  float* X0 = (float*)d_ws;
  float* X1 = X0 + NS;
  float* Q = X0 + 2 * NS;
  unsigned char* KV = (unsigned char*)(X0 + 3 * NS);  // NN*192 bytes
  int* counts = (int*)(X0 + 3 * NS + NS / 2);  // NN
  int* excl = counts + NN;                     // NN
  int* btot = excl + NN;                       // 256
  int* boff = btot + 256;                      // 256
  int* rowptr = boff + 256;                    // NN+1
  int* cursor = rowptr + NN + 1;               // NN
  int* csr_src = cursor + NN;                  // EE
  float* G = (float*)(csr_src + EE);           // 64*64

  // ---- CSR build (dst shared by all layers) ----
  hipMemsetAsync(counts, 0, NN * sizeof(int), stream);
  k_count<<<(EE + 255) / 256, 256, 0, stream>>>(ei, counts);
  k_scanA<<<NB_SCAN, 256, 0, stream>>>(counts, excl, btot);
  k_scanB<<<1, 256, 0, stream>>>(btot, boff);
  k_scanC<<<NB_SCAN, 256, 0, stream>>>(excl, boff, rowptr, cursor);
  k_scatter<<<(EE + 255) / 256, 256, 0, stream>>>(ei, cursor, csr_src);

  const dim3 gq((NN + 63) / 64, 4);
  const int nwb = (NN * 64 + 255) / 256;  // one wave per node
  // layer 0: FIN=16 HC=96 H=3 C=32  (emb-fused in, skip/out X1)
  {
    const float* const* p = &P[0];
    k_qkvs<16, 96, true><<<gq, 256, 0, stream>>>(
        nullptr, node_idx, emb, p[0], p[1], p[2], p[3], p[4], p[5], p[6], p[7],
        Q, KV, X1);
    k_agg<3, 32><<<nwb, 256, 0, stream>>>(rowptr, csr_src, Q, KV, X1);
  }
  // layer 1: FIN=96 HC=96 H=1 C=96  (in X1, skip/out X0)
  {
    const float* const* p = &P[8];
    k_qkvs<96, 96, false><<<gq, 256, 0, stream>>>(
        X1, nullptr, nullptr, p[0], p[1], p[2], p[3], p[4], p[5], p[6], p[7],
        Q, KV, X0);
    k_agg<1, 96><<<nwb, 256, 0, stream>>>(rowptr, csr_src, Q, KV, X0);
  }
  // layer 2: FIN=96 HC=64 H=1 C=64  (in X0, skip/out X1)
  {
    const float* const* p = &P[16];
    k_qkvs<96, 64, false><<<gq, 256, 0, stream>>>(
        X0, nullptr, nullptr, p[0], p[1], p[2], p[3], p[4], p[5], p[6], p[7],
        Q, KV, X1);
    k_agg<1, 64><<<nwb, 256, 0, stream>>>(rowptr, csr_src, Q, KV, X1);
  }

  k_pool<<<BB, 256, 0, stream>>>(X1, batch, G);
  k_mlp<<<1, 64, 0, stream>>>(G, demo, W1, b1, W2, b2, (float*)d_out);
}

// Round 8
// 333.062 us; speedup vs baseline: 35.3368x; 1.2661x over previous
//
#include <hip/hip_runtime.h>
#include <hip/hip_bf16.h>

#define NN 50000
#define EE 800000
#define BB 64

typedef float fx2 __attribute__((ext_vector_type(2)));
typedef short short8 __attribute__((ext_vector_type(8)));
typedef float floatx4 __attribute__((ext_vector_type(4)));

__device__ __forceinline__ short f2bs(float f) {
  __hip_bfloat16 h = __float2bfloat16(f);
  short s;
  __builtin_memcpy(&s, &h, 2);
  return s;
}

// ---------------- K1: MFMA q,k,v,skip GEMMs; blockIdx.y selects matrix ----
// W staged to LDS transposed+bf16, stride padded (2-way bank = free).
// A frag: row=lane&15, k=(lane>>4)*8+j. C/D: col=lane&15, row=(lane>>4)*4+r.
// K,V outputs packed fp8 e4m3 into interleaved KV rows [K(HC) | V(HC)].
template <int FIN, int HC, bool EMB>
__global__ __launch_bounds__(256) void k_qkvs(
    const float* __restrict__ x, const int* __restrict__ node_idx,
    const float* __restrict__ emb, const float* __restrict__ Wq,
    const float* __restrict__ Wk, const float* __restrict__ Wv,
    const float* __restrict__ Ws, const float* __restrict__ bq,
    const float* __restrict__ bk, const float* __restrict__ bv,
    const float* __restrict__ bs, float* __restrict__ q,
    unsigned char* __restrict__ kv, float* __restrict__ skip) {
  constexpr int KT = (FIN + 31) / 32;   // K-steps of 32 (zero-padded tail)
  constexpr int NT = HC / 16;           // 16-wide N tiles
  constexpr int PSTR = KT * 32 + 8;     // padded LDS row stride (bf16 elems)
  __shared__ short wt[HC * PSTR];       // W^T bf16: wt[col][k]
  const int m = blockIdx.y;             // 0=q 1=k 2=v 3=skip
  const float* __restrict__ Wm = (m == 0) ? Wq : (m == 1) ? Wk : (m == 2) ? Wv : Ws;
  const float* __restrict__ bm = (m == 0) ? bq : (m == 1) ? bk : (m == 2) ? bv : bs;
  // zero-fill (covers K pad), then stage W transposed as bf16
  for (int i = threadIdx.x; i < HC * PSTR / 2; i += 256) ((int*)wt)[i] = 0;
  __syncthreads();
  for (int i = threadIdx.x; i < FIN * HC; i += 256) {
    const int k = i / HC, c = i - k * HC;
    wt[c * PSTR + k] = f2bs(Wm[i]);
  }
  __syncthreads();

  const int lane = threadIdx.x & 63;
  const int wid = threadIdx.x >> 6;
  const int fr = lane & 15;   // A-row / D-col within tile
  const int kg = lane >> 4;   // k-group (8 elems) / D row-group (4 rows)
  const int node0 = blockIdx.x * 64 + wid * 16;
  int arow = node0 + fr;
  if (arow > NN - 1) arow = NN - 1;
  const float* __restrict__ xr =
      EMB ? emb + (size_t)node_idx[arow] * 16 : x + (size_t)arow * FIN;

  floatx4 acc[NT];
#pragma unroll
  for (int nt = 0; nt < NT; ++nt) {
    const float b = bm[nt * 16 + fr];  // bias per D-col, splat across rows
#pragma unroll
    for (int r = 0; r < 4; ++r) acc[nt][r] = b;
  }

#pragma unroll
  for (int kt = 0; kt < KT; ++kt) {
    const int kbase = kt * 32 + kg * 8;
    short8 a = {0, 0, 0, 0, 0, 0, 0, 0};
    if (kbase < FIN) {
      const float4 xa = *(const float4*)(xr + kbase);
      const float4 xb = *(const float4*)(xr + kbase + 4);
      a[0] = f2bs(xa.x); a[1] = f2bs(xa.y); a[2] = f2bs(xa.z); a[3] = f2bs(xa.w);
      a[4] = f2bs(xb.x); a[5] = f2bs(xb.y); a[6] = f2bs(xb.z); a[7] = f2bs(xb.w);
    }
#pragma unroll
    for (int nt = 0; nt < NT; ++nt) {
      const short8 bfr =
          *(const short8*)(&wt[(nt * 16 + fr) * PSTR + kt * 32 + kg * 8]);
      acc[nt] =
          __builtin_amdgcn_mfma_f32_16x16x32_bf16(a, bfr, acc[nt], 0, 0, 0);
    }
  }

#pragma unroll
  for (int nt = 0; nt < NT; ++nt) {
    const int ch = nt * 16 + fr;
#pragma unroll
    for (int r = 0; r < 4; ++r) {
      const int node = node0 + kg * 4 + r;
      if (node >= NN) continue;
      const float val = acc[nt][r];
      if (m == 1 || m == 2) {
        const int w = __builtin_amdgcn_cvt_pk_fp8_f32(val, val, 0, false);
        kv[(size_t)node * (2 * HC) + (m == 2 ? HC : 0) + ch] =
            (unsigned char)(w & 0xff);
      } else {
        (m == 0 ? q : skip)[(size_t)node * HC + ch] = val;
      }
    }
  }
}

// ---------------- CSR build ----------------
__global__ void k_count(const int* __restrict__ ei, int* __restrict__ counts) {
  int e = blockIdx.x * 256 + threadIdx.x;
  if (e >= EE) return;
  atomicAdd(&counts[ei[EE + e]], 1);
}

__global__ void k_scanA(const int* __restrict__ counts, int* __restrict__ excl,
                        int* __restrict__ btot) {
  __shared__ int s[256];
  const int tid = threadIdx.x;
  const int i = blockIdx.x * 256 + tid;
  int v = (i < NN) ? counts[i] : 0;
  s[tid] = v;
  __syncthreads();
  for (int off = 1; off < 256; off <<= 1) {
    int t = (tid >= off) ? s[tid - off] : 0;
    __syncthreads();
    s[tid] += t;
    __syncthreads();
  }
  if (i < NN) excl[i] = s[tid] - v;
  if (tid == 255) btot[blockIdx.x] = s[255];
}

#define NB_SCAN ((NN + 255) / 256)

__global__ void k_scanB(const int* __restrict__ btot, int* __restrict__ boff) {
  __shared__ int s[256];
  const int tid = threadIdx.x;
  int v = (tid < NB_SCAN) ? btot[tid] : 0;
  s[tid] = v;
  __syncthreads();
  for (int off = 1; off < 256; off <<= 1) {
    int t = (tid >= off) ? s[tid - off] : 0;
    __syncthreads();
    s[tid] += t;
    __syncthreads();
  }
  if (tid < NB_SCAN) boff[tid] = s[tid] - v;
}

__global__ void k_scanC(const int* __restrict__ excl,
                        const int* __restrict__ boff,
                        int* __restrict__ rowptr, int* __restrict__ cursor) {
  const int i = blockIdx.x * 256 + threadIdx.x;
  if (i < NN) {
    int r = excl[i] + boff[blockIdx.x];
    rowptr[i] = r;
    cursor[i] = r;
  }
  if (i == 0) rowptr[NN] = EE;
}

__global__ void k_scatter(const int* __restrict__ ei, int* __restrict__ cursor,
                          int* __restrict__ csr_src) {
  int e = blockIdx.x * 256 + threadIdx.x;
  if (e >= EE) return;
  int d = ei[EE + e];
  int p = atomicAdd(&cursor[d], 1);
  csr_src[p] = ei[e];
}

// ---------------- K2: merged-head gather aggregation, fp8 KV --------------
constexpr float scale_of(int c) {
  return c == 32 ? 0.17677669529663687f
                 : (c == 64 ? 0.125f : 0.10206207261596575f);
}

template <int H, int C>
__global__ __launch_bounds__(256) void k_agg(
    const int* __restrict__ rowptr, const int* __restrict__ csr_src,
    const float* __restrict__ q, const unsigned char* __restrict__ kv,
    float* __restrict__ xout) {
  constexpr int HC = H * C;
  constexpr int ROW = HC / 4;               // active lanes per group
  constexpr int LG = (ROW > 16) ? 32 : 16;  // group width (pow2)
  constexpr int G = 64 / LG;                // edge groups per wave
  constexpr int RW = (H == 1) ? LG : 8;     // dot-reduce width (seg per head)
  const int n = blockIdx.x * (256 / 64) + (threadIdx.x >> 6);
  if (n >= NN) return;
  const int lane = threadIdx.x & 63;
  const int g = lane / LG;
  const int cl = lane % LG;
  const bool act = cl < ROW;
  float4 qr = {0.f, 0.f, 0.f, 0.f};
  if (act) qr = ((const float4*)(q + (size_t)n * HC))[cl];
  const unsigned coff = 4u * (unsigned)cl;
  float4 acc = {0.f, 0.f, 0.f, 0.f};
  float den = 0.f;
  const int lo = rowptr[n], hi = rowptr[n + 1];
  int i = lo + g;
  for (; i + G < hi; i += 2 * G) {
    const int s0 = csr_src[i];
    const int s1 = csr_src[i + G];
    const unsigned char* r0 = kv + (size_t)((unsigned)s0 * (2 * HC));
    const unsigned char* r1 = kv + (size_t)((unsigned)s1 * (2 * HC));
    int kw0 = 0, vw0 = 0, kw1 = 0, vw1 = 0;
    if (act) {
      kw0 = *(const int*)(r0 + coff);
      vw0 = *(const int*)(r0 + HC + coff);
      kw1 = *(const int*)(r1 + coff);
      vw1 = *(const int*)(r1 + HC + coff);
    }
    fx2 a0 = __builtin_amdgcn_cvt_pk_f32_fp8(kw0, false);
    fx2 b0 = __builtin_amdgcn_cvt_pk_f32_fp8(kw0, true);
    fx2 a1 = __builtin_amdgcn_cvt_pk_f32_fp8(kw1, false);
    fx2 b1 = __builtin_amdgcn_cvt_pk_f32_fp8(kw1, true);
    float d0 = qr.x * a0.x + qr.y * a0.y + qr.z * b0.x + qr.w * b0.y;
    float d1 = qr.x * a1.x + qr.y * a1.y + qr.z * b1.x + qr.w * b1.y;
#pragma unroll
    for (int m = 1; m < RW; m <<= 1) {
      d0 += __shfl_xor(d0, m);
      d1 += __shfl_xor(d1, m);
    }
    const float e0 = __expf(d0 * scale_of(C));
    const float e1 = __expf(d1 * scale_of(C));
    den += e0 + e1;
    fx2 va0 = __builtin_amdgcn_cvt_pk_f32_fp8(vw0, false);
    fx2 vb0 = __builtin_amdgcn_cvt_pk_f32_fp8(vw0, true);
    fx2 va1 = __builtin_amdgcn_cvt_pk_f32_fp8(vw1, false);
    fx2 vb1 = __builtin_amdgcn_cvt_pk_f32_fp8(vw1, true);
    acc.x += e0 * va0.x + e1 * va1.x;
    acc.y += e0 * va0.y + e1 * va1.y;
    acc.z += e0 * vb0.x + e1 * vb1.x;
    acc.w += e0 * vb0.y + e1 * vb1.y;
  }
  if (i < hi) {
    const int s0 = csr_src[i];
    const unsigned char* r0 = kv + (size_t)((unsigned)s0 * (2 * HC));
    int kw0 = 0, vw0 = 0;
    if (act) {
      kw0 = *(const int*)(r0 + coff);
      vw0 = *(const int*)(r0 + HC + coff);
    }
    fx2 a0 = __builtin_amdgcn_cvt_pk_f32_fp8(kw0, false);
    fx2 b0 = __builtin_amdgcn_cvt_pk_f32_fp8(kw0, true);
    float d0 = qr.x * a0.x + qr.y * a0.y + qr.z * b0.x + qr.w * b0.y;
#pragma unroll
    for (int m = 1; m < RW; m <<= 1) d0 += __shfl_xor(d0, m);
    const float e0 = __expf(d0 * scale_of(C));
    den += e0;
    fx2 va0 = __builtin_amdgcn_cvt_pk_f32_fp8(vw0, false);
    fx2 vb0 = __builtin_amdgcn_cvt_pk_f32_fp8(vw0, true);
    acc.x += e0 * va0.x;
    acc.y += e0 * va0.y;
    acc.z += e0 * vb0.x;
    acc.w += e0 * vb0.y;
  }
#pragma unroll
  for (int m = LG; m < 64; m <<= 1) {
    den += __shfl_xor(den, m);
    acc.x += __shfl_xor(acc.x, m);
    acc.y += __shfl_xor(acc.y, m);
    acc.z += __shfl_xor(acc.z, m);
    acc.w += __shfl_xor(acc.w, m);
  }
  if (lane < ROW) {
    const float inv = 1.f / (den + 1e-16f);
    float4* o = (float4*)(xout + (size_t)n * HC);
    float4 c = o[lane];
    c.x += acc.x * inv;
    c.y += acc.y * inv;
    c.z += acc.z * inv;
    c.w += acc.w * inv;
    o[lane] = c;
  }
}

// ---------------- K4: fused segment-mean pool + MLP ----------------
__device__ __forceinline__ int lowerb(const int* __restrict__ b, int n,
                                      int key) {
  int lo = 0, hi = n;
  while (lo < hi) {
    int mid = (lo + hi) >> 1;
    if (b[mid] < key) lo = mid + 1;
    else hi = mid;
  }
  return lo;
}

__global__ void k_poolmlp(const float* __restrict__ x,
                          const int* __restrict__ batch,
                          const float* __restrict__ demo,
                          const float* __restrict__ W1,
                          const float* __restrict__ b1,
                          const float* __restrict__ W2,
                          const float* __restrict__ b2,
                          float* __restrict__ out) {
  const int b = blockIdx.x;
  const int lo = lowerb(batch, NN, b);
  const int hi = lowerb(batch, NN, b + 1);
  const int j = threadIdx.x & 63;
  const int r = threadIdx.x >> 6;
  float acc = 0.f;
  for (int n = lo + r; n < hi; n += 4) acc += x[(size_t)n * 64 + j];
  __shared__ float red[256];
  __shared__ float gsh[64];
  __shared__ float hsh[32];
  red[threadIdx.x] = acc;
  __syncthreads();
  if (threadIdx.x < 64) {
    float s = red[j] + red[64 + j] + red[128 + j] + red[192 + j];
    gsh[j] = s / (float)max(hi - lo, 1);
  }
  __syncthreads();
  if (threadIdx.x < 32) {
    float h = b1[threadIdx.x];
    for (int t = 0; t < 64; ++t) h += gsh[t] * W1[t * 32 + threadIdx.x];
    for (int t = 0; t < 5; ++t)
      h += demo[b * 5 + t] * W1[(64 + t) * 32 + threadIdx.x];
    hsh[threadIdx.x] = fmaxf(h, 0.f);
  }
  __syncthreads();
  if (threadIdx.x < 2) {
    float o = b2[threadIdx.x];
    for (int jm = 0; jm < 32; ++jm) o += hsh[jm] * W2[jm * 2 + threadIdx.x];
    out[b * 2 + threadIdx.x] = o;
  }
}

extern "C" void kernel_launch(void* const* d_in, const int* in_sizes, int n_in,
                              void* d_out, int out_size, void* d_ws,
                              size_t ws_size, hipStream_t stream) {
  const int* node_idx = (const int*)d_in[0];
  const int* ei = (const int*)d_in[1];
  const int* batch = (const int*)d_in[2];
  const float* demo = (const float*)d_in[3];
  const float* emb = (const float*)d_in[4];
  const float* P[24];
  for (int i = 0; i < 24; ++i) P[i] = (const float*)d_in[5 + i];
  const float* W1 = (const float*)d_in[29];
  const float* b1 = (const float*)d_in[30];
  const float* W2 = (const float*)d_in[31];
  const float* b2 = (const float*)d_in[32];

  const size_t NS = (size_t)NN * 96;
  float* X0 = (float*)d_ws;
  float* X1 = X0 + NS;
  float* Q = X0 + 2 * NS;
  unsigned char* KV = (unsigned char*)(X0 + 3 * NS);  // NN*192 bytes
  int* counts = (int*)(X0 + 3 * NS + NS / 2);  // NN
  int* excl = counts + NN;                     // NN
  int* btot = excl + NN;                       // 256
  int* boff = btot + 256;                      // 256
  int* rowptr = boff + 256;                    // NN+1
  int* cursor = rowptr + NN + 1;               // NN
  int* csr_src = cursor + NN;                  // EE

  // ---- CSR build (dst shared by all layers) ----
  hipMemsetAsync(counts, 0, NN * sizeof(int), stream);
  k_count<<<(EE + 255) / 256, 256, 0, stream>>>(ei, counts);
  k_scanA<<<NB_SCAN, 256, 0, stream>>>(counts, excl, btot);
  k_scanB<<<1, 256, 0, stream>>>(btot, boff);
  k_scanC<<<NB_SCAN, 256, 0, stream>>>(excl, boff, rowptr, cursor);
  k_scatter<<<(EE + 255) / 256, 256, 0, stream>>>(ei, cursor, csr_src);

  const dim3 gq((NN + 63) / 64, 4);
  const int nwb = (NN * 64 + 255) / 256;  // one wave per node
  // layer 0: FIN=16 HC=96 H=3 C=32  (emb-fused in, skip/out X1)
  {
    const float* const* p = &P[0];
    k_qkvs<16, 96, true><<<gq, 256, 0, stream>>>(
        nullptr, node_idx, emb, p[0], p[1], p[2], p[3], p[4], p[5], p[6], p[7],
        Q, KV, X1);
    k_agg<3, 32><<<nwb, 256, 0, stream>>>(rowptr, csr_src, Q, KV, X1);
  }
  // layer 1: FIN=96 HC=96 H=1 C=96  (in X1, skip/out X0)
  {
    const float* const* p = &P[8];
    k_qkvs<96, 96, false><<<gq, 256, 0, stream>>>(
        X1, nullptr, nullptr, p[0], p[1], p[2], p[3], p[4], p[5], p[6], p[7],
        Q, KV, X0);
    k_agg<1, 96><<<nwb, 256, 0, stream>>>(rowptr, csr_src, Q, KV, X0);
  }
  // layer 2: FIN=96 HC=64 H=1 C=64  (in X0, skip/out X1)
  {
    const float* const* p = &P[16];
    k_qkvs<96, 64, false><<<gq, 256, 0, stream>>>(
        X0, nullptr, nullptr, p[0], p[1], p[2], p[3], p[4], p[5], p[6], p[7],
        Q, KV, X1);
    k_agg<1, 64><<<nwb, 256, 0, stream>>>(rowptr, csr_src, Q, KV, X1);
  }

  k_poolmlp<<<BB, 256, 0, stream>>>(X1, batch, demo, W1, b1, W2, b2,
                                    (float*)d_out);
}

// Round 9
// 319.516 us; speedup vs baseline: 36.8350x; 1.0424x over previous
//
#include <hip/hip_runtime.h>
#include <hip/hip_bf16.h>

#define NN 50000
#define EE 800000
#define BB 64

typedef float fx2 __attribute__((ext_vector_type(2)));
typedef short short8 __attribute__((ext_vector_type(8)));
typedef float floatx4 __attribute__((ext_vector_type(4)));

__device__ __forceinline__ short f2bs(float f) {
  __hip_bfloat16 h = __float2bfloat16(f);
  short s;
  __builtin_memcpy(&s, &h, 2);
  return s;
}

// ---------------- K1: MFMA q,k,v,skip GEMMs; blockIdx.y selects matrix ----
template <int FIN, int HC, bool EMB>
__global__ __launch_bounds__(256) void k_qkvs(
    const float* __restrict__ x, const int* __restrict__ node_idx,
    const float* __restrict__ emb, const float* __restrict__ Wq,
    const float* __restrict__ Wk, const float* __restrict__ Wv,
    const float* __restrict__ Ws, const float* __restrict__ bq,
    const float* __restrict__ bk, const float* __restrict__ bv,
    const float* __restrict__ bs, float* __restrict__ q,
    unsigned char* __restrict__ kv, float* __restrict__ skip) {
  constexpr int KT = (FIN + 31) / 32;   // K-steps of 32 (zero-padded tail)
  constexpr int NT = HC / 16;           // 16-wide N tiles
  constexpr int PSTR = KT * 32 + 8;     // padded LDS row stride (bf16 elems)
  __shared__ short wt[HC * PSTR];       // W^T bf16: wt[col][k]
  const int m = blockIdx.y;             // 0=q 1=k 2=v 3=skip
  const float* __restrict__ Wm = (m == 0) ? Wq : (m == 1) ? Wk : (m == 2) ? Wv : Ws;
  const float* __restrict__ bm = (m == 0) ? bq : (m == 1) ? bk : (m == 2) ? bv : bs;
  for (int i = threadIdx.x; i < HC * PSTR / 2; i += 256) ((int*)wt)[i] = 0;
  __syncthreads();
  for (int i = threadIdx.x; i < FIN * HC; i += 256) {
    const int k = i / HC, c = i - k * HC;
    wt[c * PSTR + k] = f2bs(Wm[i]);
  }
  __syncthreads();

  const int lane = threadIdx.x & 63;
  const int wid = threadIdx.x >> 6;
  const int fr = lane & 15;   // A-row / D-col within tile
  const int kg = lane >> 4;   // k-group (8 elems) / D row-group (4 rows)
  const int node0 = blockIdx.x * 64 + wid * 16;
  int arow = node0 + fr;
  if (arow > NN - 1) arow = NN - 1;
  const float* __restrict__ xr =
      EMB ? emb + (size_t)node_idx[arow] * 16 : x + (size_t)arow * FIN;

  floatx4 acc[NT];
#pragma unroll
  for (int nt = 0; nt < NT; ++nt) {
    const float b = bm[nt * 16 + fr];  // bias per D-col, splat across rows
#pragma unroll
    for (int r = 0; r < 4; ++r) acc[nt][r] = b;
  }

#pragma unroll
  for (int kt = 0; kt < KT; ++kt) {
    const int kbase = kt * 32 + kg * 8;
    short8 a = {0, 0, 0, 0, 0, 0, 0, 0};
    if (kbase < FIN) {
      const float4 xa = *(const float4*)(xr + kbase);
      const float4 xb = *(const float4*)(xr + kbase + 4);
      a[0] = f2bs(xa.x); a[1] = f2bs(xa.y); a[2] = f2bs(xa.z); a[3] = f2bs(xa.w);
      a[4] = f2bs(xb.x); a[5] = f2bs(xb.y); a[6] = f2bs(xb.z); a[7] = f2bs(xb.w);
    }
#pragma unroll
    for (int nt = 0; nt < NT; ++nt) {
      const short8 bfr =
          *(const short8*)(&wt[(nt * 16 + fr) * PSTR + kt * 32 + kg * 8]);
      acc[nt] =
          __builtin_amdgcn_mfma_f32_16x16x32_bf16(a, bfr, acc[nt], 0, 0, 0);
    }
  }

#pragma unroll
  for (int nt = 0; nt < NT; ++nt) {
    const int ch = nt * 16 + fr;
#pragma unroll
    for (int r = 0; r < 4; ++r) {
      const int node = node0 + kg * 4 + r;
      if (node >= NN) continue;
      const float val = acc[nt][r];
      if (m == 1 || m == 2) {
        const int w = __builtin_amdgcn_cvt_pk_fp8_f32(val, val, 0, false);
        kv[(size_t)node * (2 * HC) + (m == 2 ? HC : 0) + ch] =
            (unsigned char)(w & 0xff);
      } else {
        (m == 0 ? q : skip)[(size_t)node * HC + ch] = val;
      }
    }
  }
}

// ---------------- CSR build ----------------
__global__ void k_count(const int* __restrict__ ei, int* __restrict__ counts) {
  int e = blockIdx.x * 256 + threadIdx.x;
  if (e >= EE) return;
  atomicAdd(&counts[ei[EE + e]], 1);
}

__global__ void k_scanA(const int* __restrict__ counts, int* __restrict__ excl,
                        int* __restrict__ btot) {
  __shared__ int s[256];
  const int tid = threadIdx.x;
  const int i = blockIdx.x * 256 + tid;
  int v = (i < NN) ? counts[i] : 0;
  s[tid] = v;
  __syncthreads();
  for (int off = 1; off < 256; off <<= 1) {
    int t = (tid >= off) ? s[tid - off] : 0;
    __syncthreads();
    s[tid] += t;
    __syncthreads();
  }
  if (i < NN) excl[i] = s[tid] - v;
  if (tid == 255) btot[blockIdx.x] = s[255];
}

#define NB_SCAN ((NN + 255) / 256)

__global__ void k_scanB(const int* __restrict__ btot, int* __restrict__ boff) {
  __shared__ int s[256];
  const int tid = threadIdx.x;
  int v = (tid < NB_SCAN) ? btot[tid] : 0;
  s[tid] = v;
  __syncthreads();
  for (int off = 1; off < 256; off <<= 1) {
    int t = (tid >= off) ? s[tid - off] : 0;
    __syncthreads();
    s[tid] += t;
    __syncthreads();
  }
  if (tid < NB_SCAN) boff[tid] = s[tid] - v;
}

__global__ void k_scanC(const int* __restrict__ excl,
                        const int* __restrict__ boff,
                        int* __restrict__ rowptr, int* __restrict__ cursor) {
  const int i = blockIdx.x * 256 + threadIdx.x;
  if (i < NN) {
    int r = excl[i] + boff[blockIdx.x];
    rowptr[i] = r;
    cursor[i] = r;
  }
  if (i == 0) rowptr[NN] = EE;
}

__global__ void k_scatter(const int* __restrict__ ei, int* __restrict__ cursor,
                          int* __restrict__ csr_src) {
  int e = blockIdx.x * 256 + threadIdx.x;
  if (e >= EE) return;
  int d = ei[EE + e];
  int p = atomicAdd(&cursor[d], 1);
  csr_src[p] = ei[e];
}

// ---------------- K2: merged-head gather aggregation, fp8 KV --------------
constexpr float scale_of(int c) {
  return c == 32 ? 0.17677669529663687f
                 : (c == 64 ? 0.125f : 0.10206207261596575f);
}

template <int H, int C>
__global__ __launch_bounds__(256) void k_agg(
    const int* __restrict__ rowptr, const int* __restrict__ csr_src,
    const float* __restrict__ q, const unsigned char* __restrict__ kv,
    float* __restrict__ xout) {
  constexpr int HC = H * C;
  constexpr int ROW = HC / 4;               // active lanes per group
  constexpr int LG = (ROW > 16) ? 32 : 16;  // group width (pow2)
  constexpr int G = 64 / LG;                // edge groups per wave
  constexpr int RW = (H == 1) ? LG : 8;     // dot-reduce width (seg per head)
  const int n = blockIdx.x * (256 / 64) + (threadIdx.x >> 6);
  if (n >= NN) return;
  const int lane = threadIdx.x & 63;
  const int g = lane / LG;
  const int cl = lane % LG;
  const bool act = cl < ROW;
  float4 qr = {0.f, 0.f, 0.f, 0.f};
  if (act) qr = ((const float4*)(q + (size_t)n * HC))[cl];
  const unsigned coff = 4u * (unsigned)cl;
  float4 acc = {0.f, 0.f, 0.f, 0.f};
  float den = 0.f;
  const int lo = rowptr[n], hi = rowptr[n + 1];
  int i = lo + g;
  for (; i + G < hi; i += 2 * G) {
    const int s0 = csr_src[i];
    const int s1 = csr_src[i + G];
    const unsigned char* r0 = kv + (size_t)((unsigned)s0 * (2 * HC));
    const unsigned char* r1 = kv + (size_t)((unsigned)s1 * (2 * HC));
    int kw0 = 0, vw0 = 0, kw1 = 0, vw1 = 0;
    if (act) {
      kw0 = *(const int*)(r0 + coff);
      vw0 = *(const int*)(r0 + HC + coff);
      kw1 = *(const int*)(r1 + coff);
      vw1 = *(const int*)(r1 + HC + coff);
    }
    fx2 a0 = __builtin_amdgcn_cvt_pk_f32_fp8(kw0, false);
    fx2 b0 = __builtin_amdgcn_cvt_pk_f32_fp8(kw0, true);
    fx2 a1 = __builtin_amdgcn_cvt_pk_f32_fp8(kw1, false);
    fx2 b1 = __builtin_amdgcn_cvt_pk_f32_fp8(kw1, true);
    float d0 = qr.x * a0.x + qr.y * a0.y + qr.z * b0.x + qr.w * b0.y;
    float d1 = qr.x * a1.x + qr.y * a1.y + qr.z * b1.x + qr.w * b1.y;
#pragma unroll
    for (int m = 1; m < RW; m <<= 1) {
      d0 += __shfl_xor(d0, m);
      d1 += __shfl_xor(d1, m);
    }
    const float e0 = __expf(d0 * scale_of(C));
    const float e1 = __expf(d1 * scale_of(C));
    den += e0 + e1;
    fx2 va0 = __builtin_amdgcn_cvt_pk_f32_fp8(vw0, false);
    fx2 vb0 = __builtin_amdgcn_cvt_pk_f32_fp8(vw0, true);
    fx2 va1 = __builtin_amdgcn_cvt_pk_f32_fp8(vw1, false);
    fx2 vb1 = __builtin_amdgcn_cvt_pk_f32_fp8(vw1, true);
    acc.x += e0 * va0.x + e1 * va1.x;
    acc.y += e0 * va0.y + e1 * va1.y;
    acc.z += e0 * vb0.x + e1 * vb1.x;
    acc.w += e0 * vb0.y + e1 * vb1.y;
  }
  if (i < hi) {
    const int s0 = csr_src[i];
    const unsigned char* r0 = kv + (size_t)((unsigned)s0 * (2 * HC));
    int kw0 = 0, vw0 = 0;
    if (act) {
      kw0 = *(const int*)(r0 + coff);
      vw0 = *(const int*)(r0 + HC + coff);
    }
    fx2 a0 = __builtin_amdgcn_cvt_pk_f32_fp8(kw0, false);
    fx2 b0 = __builtin_amdgcn_cvt_pk_f32_fp8(kw0, true);
    float d0 = qr.x * a0.x + qr.y * a0.y + qr.z * b0.x + qr.w * b0.y;
#pragma unroll
    for (int m = 1; m < RW; m <<= 1) d0 += __shfl_xor(d0, m);
    const float e0 = __expf(d0 * scale_of(C));
    den += e0;
    fx2 va0 = __builtin_amdgcn_cvt_pk_f32_fp8(vw0, false);
    fx2 vb0 = __builtin_amdgcn_cvt_pk_f32_fp8(vw0, true);
    acc.x += e0 * va0.x;
    acc.y += e0 * va0.y;
    acc.z += e0 * vb0.x;
    acc.w += e0 * vb0.y;
  }
#pragma unroll
  for (int m = LG; m < 64; m <<= 1) {
    den += __shfl_xor(den, m);
    acc.x += __shfl_xor(acc.x, m);
    acc.y += __shfl_xor(acc.y, m);
    acc.z += __shfl_xor(acc.z, m);
    acc.w += __shfl_xor(acc.w, m);
  }
  if (lane < ROW) {
    const float inv = 1.f / (den + 1e-16f);
    float4* o = (float4*)(xout + (size_t)n * HC);
    float4 c = o[lane];
    c.x += acc.x * inv;
    c.y += acc.y * inv;
    c.z += acc.z * inv;
    c.w += acc.w * inv;
    o[lane] = c;
  }
}

// ---------------- K4: parallel segment-sum pool (graph x 16 chunks) -------
__device__ __forceinline__ int lowerb(const int* __restrict__ b, int n,
                                      int key) {
  int lo = 0, hi = n;
  while (lo < hi) {
    int mid = (lo + hi) >> 1;
    if (b[mid] < key) lo = mid + 1;
    else hi = mid;
  }
  return lo;
}

#define SPL 16

__global__ __launch_bounds__(256) void k_pool(const float* __restrict__ x,
                                              const int* __restrict__ batch,
                                              float* __restrict__ gsum) {
  const int b = blockIdx.x >> 4;
  const int s = blockIdx.x & (SPL - 1);
  const int lo = lowerb(batch, NN, b);
  const int hi = lowerb(batch, NN, b + 1);
  const int len = hi - lo;
  const int st = lo + (int)(((long long)len * s) / SPL);
  const int en = lo + (int)(((long long)len * (s + 1)) / SPL);
  const int j = threadIdx.x & 63;
  const int r = threadIdx.x >> 6;
  float acc = 0.f;
  for (int n = st + r; n < en; n += 4) acc += x[(size_t)n * 64 + j];
  __shared__ float red[256];
  red[threadIdx.x] = acc;
  __syncthreads();
  if (threadIdx.x < 64) {
    float v = red[j] + red[64 + j] + red[128 + j] + red[192 + j];
    if (v != 0.f) atomicAdd(&gsum[b * 64 + j], v);
  }
}

// ---------------- K5: final MLP (divide-by-count folded in) ----------------
__global__ void k_mlp(const float* __restrict__ gsum,
                      const int* __restrict__ batch,
                      const float* __restrict__ demo,
                      const float* __restrict__ W1,
                      const float* __restrict__ b1,
                      const float* __restrict__ W2,
                      const float* __restrict__ b2, float* __restrict__ out) {
  const int b = threadIdx.x;
  if (b >= BB) return;
  const int lo = lowerb(batch, NN, b);
  const int hi = lowerb(batch, NN, b + 1);
  const float inv = 1.f / (float)max(hi - lo, 1);
  float f[69];
#pragma unroll
  for (int t = 0; t < 64; ++t) f[t] = gsum[b * 64 + t] * inv;
#pragma unroll
  for (int t = 0; t < 5; ++t) f[64 + t] = demo[b * 5 + t];
  float o0 = b2[0], o1 = b2[1];
  for (int jm = 0; jm < 32; ++jm) {
    float h = b1[jm];
#pragma unroll
    for (int t = 0; t < 69; ++t) h += f[t] * W1[t * 32 + jm];
    h = fmaxf(h, 0.f);
    o0 += h * W2[jm * 2 + 0];
    o1 += h * W2[jm * 2 + 1];
  }
  out[b * 2 + 0] = o0;
  out[b * 2 + 1] = o1;
}

extern "C" void kernel_launch(void* const* d_in, const int* in_sizes, int n_in,
                              void* d_out, int out_size, void* d_ws,
                              size_t ws_size, hipStream_t stream) {
  const int* node_idx = (const int*)d_in[0];
  const int* ei = (const int*)d_in[1];
  const int* batch = (const int*)d_in[2];
  const float* demo = (const float*)d_in[3];
  const float* emb = (const float*)d_in[4];
  const float* P[24];
  for (int i = 0; i < 24; ++i) P[i] = (const float*)d_in[5 + i];
  const float* W1 = (const float*)d_in[29];
  const float* b1 = (const float*)d_in[30];
  const float* W2 = (const float*)d_in[31];
  const float* b2 = (const float*)d_in[32];

  const size_t NS = (size_t)NN * 96;
  float* X0 = (float*)d_ws;
  float* X1 = X0 + NS;
  float* Q = X0 + 2 * NS;
  unsigned char* KV = (unsigned char*)(X0 + 3 * NS);  // NN*192 bytes
  int* counts = (int*)(X0 + 3 * NS + NS / 2);  // NN
  int* excl = counts + NN;                     // NN
  int* btot = excl + NN;                       // 256
  int* boff = btot + 256;                      // 256
  int* rowptr = boff + 256;                    // NN+1
  int* cursor = rowptr + NN + 1;               // NN
  int* csr_src = cursor + NN;                  // EE
  float* GS = (float*)(csr_src + EE);          // 64*64 partial sums

  // ---- CSR build (dst shared by all layers) ----
  hipMemsetAsync(counts, 0, NN * sizeof(int), stream);
  hipMemsetAsync(GS, 0, BB * 64 * sizeof(float), stream);
  k_count<<<(EE + 255) / 256, 256, 0, stream>>>(ei, counts);
  k_scanA<<<NB_SCAN, 256, 0, stream>>>(counts, excl, btot);
  k_scanB<<<1, 256, 0, stream>>>(btot, boff);
  k_scanC<<<NB_SCAN, 256, 0, stream>>>(excl, boff, rowptr, cursor);
  k_scatter<<<(EE + 255) / 256, 256, 0, stream>>>(ei, cursor, csr_src);

  const dim3 gq((NN + 63) / 64, 4);
  const int nwb = (NN * 64 + 255) / 256;  // one wave per node
  // layer 0: FIN=16 HC=96 H=3 C=32  (emb-fused in, skip/out X1)
  {
    const float* const* p = &P[0];
    k_qkvs<16, 96, true><<<gq, 256, 0, stream>>>(
        nullptr, node_idx, emb, p[0], p[1], p[2], p[3], p[4], p[5], p[6], p[7],
        Q, KV, X1);
    k_agg<3, 32><<<nwb, 256, 0, stream>>>(rowptr, csr_src, Q, KV, X1);
  }
  // layer 1: FIN=96 HC=96 H=1 C=96  (in X1, skip/out X0)
  {
    const float* const* p = &P[8];
    k_qkvs<96, 96, false><<<gq, 256, 0, stream>>>(
        X1, nullptr, nullptr, p[0], p[1], p[2], p[3], p[4], p[5], p[6], p[7],
        Q, KV, X0);
    k_agg<1, 96><<<nwb, 256, 0, stream>>>(rowptr, csr_src, Q, KV, X0);
  }
  // layer 2: FIN=96 HC=64 H=1 C=64  (in X0, skip/out X1)
  {
    const float* const* p = &P[16];
    k_qkvs<96, 64, false><<<gq, 256, 0, stream>>>(
        X0, nullptr, nullptr, p[0], p[1], p[2], p[3], p[4], p[5], p[6], p[7],
        Q, KV, X1);
    k_agg<1, 64><<<nwb, 256, 0, stream>>>(rowptr, csr_src, Q, KV, X1);
  }

  k_pool<<<BB * SPL, 256, 0, stream>>>(X1, batch, GS);
  k_mlp<<<1, 64, 0, stream>>>(GS, batch, demo, W1, b1, W2, b2, (float*)d_out);
}